// Round 6
// baseline (693.784 us; speedup 1.0000x reference)
//
#include <hip/hip_runtime.h>
#include <hip/hip_bf16.h>
#include <cstdint>
#include <math.h>

#define B_ 32
#define T_ 336
#define N_ 321
#define L_ 2
#define E_ 4
#define F_ 2048
#define P_ 96
#define TPAD 352   // T padded to multiple of 32 (K of GEMM1 / proj stage1)
#define NPAD 384   // N padded to multiple of 128 (M tiles)

typedef __hip_bfloat16 bf16;
typedef __attribute__((ext_vector_type(8))) __bf16 bf16x8;
typedef __attribute__((ext_vector_type(4))) float f32x4;
typedef __attribute__((ext_vector_type(16))) float f32x16;

// h blocked layout: h[pair][nb][kg][row64][8]  (kg = f/8, j = f%8)
//   kg stride 512 els, nb stride 131072 els, pair stride 786432 els.
// W2 blocked layout: W2B[le][tb][kg][row96][8]
//   kg stride 768 els, tb stride 196608 els, le stride 786432 els.
// gemm2: R3's 2-phase double-buffered schedule (stage(k+1) before compute(k), one
// vmcnt(0)+barrier per K-step, 3 blocks/CU) + K-SPLIT waves on 32x32x16 MFMA:
// wave w owns k-slice [16w,16w+16) of each BK=64 chunk -> every staged byte is
// ds_read exactly once (LDS reads 40KB -> 20KB per block-iter), then a once-per-
// block cross-wave reduction in LDS.

__device__ __forceinline__ void async_copy16(const void* g, void* l) {
  __builtin_amdgcn_global_load_lds(
      (__attribute__((address_space(1))) void*)(uintptr_t)g,
      (__attribute__((address_space(3))) void*)(unsigned int)(uintptr_t)l,
      16, 0, 0);
}

__device__ __forceinline__ void pipe_barrier_vm0() {
  asm volatile("s_waitcnt vmcnt(0)" ::: "memory");
  __builtin_amdgcn_s_barrier();
  __builtin_amdgcn_sched_barrier(0);
}

__device__ __forceinline__ void pipe_barrier_full() {
  asm volatile("s_waitcnt vmcnt(0) lgkmcnt(0)" ::: "memory");
  __builtin_amdgcn_s_barrier();
  __builtin_amdgcn_sched_barrier(0);
}

// ---------------- transpose + cast fp32 -> bf16 (K-contiguous operand prep) ----------
__global__ void transpose_cast_kernel(const float* __restrict__ src, bf16* __restrict__ dst,
                                      int R, int C, int Rp, int Cp,
                                      long long sStride, long long dStride) {
  __shared__ float tile[32][33];
  const float* s = src + (size_t)blockIdx.z * sStride;
  bf16* d = dst + (size_t)blockIdx.z * dStride;
  int r0 = blockIdx.x * 32, c0 = blockIdx.y * 32;
  int tx = threadIdx.x, ty = threadIdx.y;
  #pragma unroll
  for (int ii = 0; ii < 4; ii++) {
    int rl = ty * 4 + ii;
    int r = r0 + rl, c = c0 + tx;
    tile[rl][tx] = (r < R && c < C) ? s[(size_t)r * C + c] : 0.f;
  }
  __syncthreads();
  #pragma unroll
  for (int ii = 0; ii < 4; ii++) {
    int cl = ty * 4 + ii;
    int cd = c0 + cl, rd = r0 + tx;
    if (cd < Cp && rd < Rp)
      d[(size_t)cd * Rp + rd] = __float2bfloat16(tile[tx][cl]);
  }
}

// ---------------- We2 -> k-blocked W2B ---------------------------------------------
// grid (F/32, 4, L*E); dst[le][tb][kg][row96][8] = We2[le][f=kg*8+j][t=tb*96+row]
__global__ void repack_w2_kernel(const float* __restrict__ src, bf16* __restrict__ dst) {
  __shared__ float tile[32][96];
  int le = blockIdx.z, tb = blockIdx.y, f0 = blockIdx.x * 32;
  int tid = threadIdx.x;
  const float* s = src + (size_t)le * F_ * T_;
  for (int idx = tid; idx < 32 * 96; idx += 256) {
    int ff = idx / 96, tt = idx % 96;
    int t = tb * 96 + tt;
    tile[ff][tt] = (t < T_) ? s[(size_t)(f0 + ff) * T_ + t] : 0.f;
  }
  __syncthreads();
  bf16* d = dst + ((size_t)le * 4 + tb) * 196608 + (size_t)(f0 >> 3) * 768;
  for (int s2 = tid; s2 < 384; s2 += 256) {
    int kgl = s2 / 96, row = s2 % 96;
    bf16 v[8];
    #pragma unroll
    for (int j = 0; j < 8; j++) v[j] = __float2bfloat16(tile[kgl * 8 + j][row]);
    *(uint4*)(d + (size_t)kgl * 768 + row * 8) = *(const uint4*)v;
  }
}

// ---------------- RevIN + initial pack: x -> out (fp32) and Abuf (bf16, padded) -----
// 512 threads: 64 n-lanes x 8 t-quarters (42 t each). Two passes over x (2nd is
// L3-hot). Abuf transpose staged through a conflict-free LDS uint tile
// (row stride 177 words, gcd(17,32)=1) then linear coalesced copy-out.
__global__ __launch_bounds__(512) void revin_kernel(const float* __restrict__ x,
                                                    float* __restrict__ out,
                                                    bf16* __restrict__ Abuf) {
  __shared__ float red[8][64][2];
  __shared__ float minv[64][2];
  __shared__ unsigned int Lt[64][177];   // 176 used cols (= TPAD/2 uints per row)

  const int b = blockIdx.x;
  const int n0 = blockIdx.y * 64;
  const int tid = threadIdx.x;
  const int nl = tid & 63, tq = tid >> 6;      // tq 0..7
  const int n = n0 + nl;
  const bool valid = (n < N_);
  const float* xp = x + ((size_t)b * T_ * N_ + n) * 3;
  const int tbeg = tq * 42, tend = tbeg + 42;  // 8*42 = 336 = T_

  // pass 1: partial sums over this thread's t-range
  float s1 = 0.f, s2 = 0.f;
  if (valid) {
    for (int t = tbeg; t < tend; t++) {
      float v = xp[(size_t)t * N_ * 3];
      s1 += v; s2 += v * v;
    }
  }
  red[tq][nl][0] = s1; red[tq][nl][1] = s2;
  __syncthreads();
  if (tid < 64) {
    float a = 0.f, c = 0.f;
    #pragma unroll
    for (int q = 0; q < 8; q++) { a += red[q][tid][0]; c += red[q][tid][1]; }
    float mu = a / (float)T_;
    float var = c / (float)T_ - mu * mu;
    minv[tid][0] = mu;
    minv[tid][1] = 1.f / sqrtf(var + 1e-5f);
  }
  // zero the pad cols (t in [336,352) -> uint cols 168..175): 64 rows x 8 cols
  {
    int r = tid >> 3, c = 168 + (tid & 7);
    Lt[r][c] = 0u;
  }
  __syncthreads();

  const float mu = minv[nl][0], inv = minv[nl][1];
  // pass 2: normalize, write out (coalesced), stage packed bf16 pairs into LDS
  for (int t = tbeg; t < tend; t += 2) {
    float v0 = 0.f, v1 = 0.f;
    if (valid) {
      v0 = (xp[(size_t)t * N_ * 3] - mu) * inv;
      v1 = (xp[(size_t)(t + 1) * N_ * 3] - mu) * inv;
      out[((size_t)b * T_ + t) * N_ + n] = v0;
      out[((size_t)b * T_ + t + 1) * N_ + n] = v1;
    }
    bf16 h0 = __float2bfloat16(v0), h1 = __float2bfloat16(v1);
    unsigned int u = (unsigned int)*(unsigned short*)&h0 |
                     ((unsigned int)*(unsigned short*)&h1 << 16);
    Lt[nl][t >> 1] = u;
  }
  __syncthreads();

  // copy-out: 64 rows x 176 uints = 11264 uints, 22 per thread, coalesced
  unsigned int* abase = (unsigned int*)(Abuf + ((size_t)b * NPAD + n0) * TPAD);
  #pragma unroll
  for (int k = 0; k < 22; k++) {
    int idx = tid + k * 512;
    int row = idx / 176, c = idx % 176;
    abase[(size_t)row * (TPAD / 2) + c] = Lt[row][c];
  }
}

// ---------------- gating step 1: colsum[b,t] = sum_n out[b,t,n] ---------------------
__global__ void gate1_kernel(const float* __restrict__ out, float* __restrict__ colsum) {
  int b = blockIdx.y;
  int w = threadIdx.x >> 6, lane = threadIdx.x & 63;
  int t = blockIdx.x * 16 + w * 4;
  #pragma unroll
  for (int i = 0; i < 4; i++, t++) {
    const float* p = out + ((size_t)b * T_ + t) * N_;
    float s = 0.f;
    for (int n = lane; n < N_; n += 64) s += p[n];
    #pragma unroll
    for (int off = 32; off; off >>= 1) s += __shfl_down(s, off);
    if (lane == 0) colsum[b * T_ + t] = s;
  }
}

// ---------------- gating step 2: logits + top-2 + softmax + cv^2 loss ---------------
__global__ void gate2_kernel(const float* __restrict__ colsum, const float* __restrict__ Wg,
                             int* __restrict__ pair_e, float* __restrict__ pair_gate,
                             float* __restrict__ loss_partial, int layer) {
  __shared__ float lg[32][4];
  __shared__ float gates[32][4];
  __shared__ float imp[4];
  int tid = threadIdx.x;
  if (tid < 128) {
    int b = tid >> 2, e = tid & 3;
    float s = 0.f;
    for (int t = 0; t < T_; t++)
      s += colsum[b * T_ + t] * Wg[(layer * T_ + t) * E_ + e];
    lg[b][e] = s / (float)N_;
  }
  __syncthreads();
  if (tid < 32) {
    float v[4];
    #pragma unroll
    for (int e = 0; e < 4; e++) v[e] = lg[tid][e];
    int i0 = 0;
    for (int e = 1; e < 4; e++) if (v[e] > v[i0]) i0 = e;     // lowest index wins ties
    int i1 = -1;
    for (int e = 0; e < 4; e++) {
      if (e == i0) continue;
      if (i1 < 0 || v[e] > v[i1]) i1 = e;
    }
    float ex = expf(v[i1] - v[i0]);
    float g0 = 1.f / (1.f + ex);
    float g1 = ex / (1.f + ex);
    pair_e[tid * 2] = i0; pair_e[tid * 2 + 1] = i1;
    pair_gate[tid * 2] = g0; pair_gate[tid * 2 + 1] = g1;
    #pragma unroll
    for (int e = 0; e < 4; e++) gates[tid][e] = 0.f;
    gates[tid][i0] = g0; gates[tid][i1] = g1;
  }
  __syncthreads();
  if (tid < 4) {
    float s = 0.f;
    for (int bb = 0; bb < 32; bb++) s += gates[bb][tid];
    imp[tid] = s;
  }
  __syncthreads();
  if (tid == 0) {
    float m = (imp[0] + imp[1] + imp[2] + imp[3]) * 0.25f;
    float va = 0.f;
    #pragma unroll
    for (int e = 0; e < 4; e++) { float d = imp[e] - m; va += d * d; }
    va *= 0.25f;
    loss_partial[layer] = 0.01f * (va / (m * m + 1e-10f));
  }
}

// ---------------- GEMM1: h[pair] = gate * relu(Abuf[b] @ We1[l,e] + be1) ------------
// h written in blocked layout (see top). 2-phase pipelined: double-buffered LDS,
// stage(k+1) before compute(k), one barrier per K-step.
__global__ __launch_bounds__(256) void gemm1_kernel(
    const bf16* __restrict__ Abuf, const bf16* __restrict__ W1T,
    const float* __restrict__ be1, const int* __restrict__ pair_e,
    const float* __restrict__ pair_gate, bf16* __restrict__ h, int layer) {
  // buf b: A = S1 + b*8192 (128x32), B = S1 + b*8192 + 4096 (128x32)
  __shared__ __align__(16) bf16 S1[16384];
  __shared__ float bias_s[128];

  const int tid = threadIdx.x;
  const int w = tid >> 6, lane = tid & 63;
  const int pair = blockIdx.z;
  const int b = pair >> 1;
  const int e = pair_e[pair];
  const float gate = pair_gate[pair];
  const int m0 = blockIdx.y * 128;  // n-dim
  const int f0 = blockIdx.x * 128;

  const bf16* Ag = Abuf + (size_t)b * NPAD * TPAD + (size_t)m0 * TPAD;
  const bf16* Bg = W1T + ((size_t)(layer * E_ + e) * F_ + f0) * TPAD;
  if (tid < 128) bias_s[tid] = be1[(size_t)(layer * E_ + e) * F_ + f0 + tid];

  f32x4 acc[4][4];
  const f32x4 zero = {0.f, 0.f, 0.f, 0.f};
  #pragma unroll
  for (int i = 0; i < 4; i++)
    #pragma unroll
    for (int j = 0; j < 4; j++) acc[i][j] = zero;

  const int wm = w >> 1, wn = w & 1;
  const int lrow = lane >> 2;          // 64B-coalesced staging
  const int lkoff = (lane & 3) * 8;
  const int quad = lane >> 4;
  const int l15 = lane & 15;

  auto stage1 = [&](int k, int buf) {
    const int k0 = k * 32;
    bf16* As = S1 + buf * 8192;
    bf16* Bs = As + 4096;
    #pragma unroll
    for (int i = 0; i < 2; i++) {
      int r = (w * 2 + i) * 16 + lrow;
      async_copy16(Ag + (size_t)r * TPAD + k0 + lkoff, As + (w * 2 + i) * 512);
      async_copy16(Bg + (size_t)r * TPAD + k0 + lkoff, Bs + (w * 2 + i) * 512);
    }
  };

  stage1(0, 0);
  pipe_barrier_full();

  for (int kk = 0; kk < TPAD / 32; ++kk) {
    if (kk < TPAD / 32 - 1) stage1(kk + 1, (kk + 1) & 1);
    const bf16* As = S1 + (kk & 1) * 8192;
    const bf16* Bs = As + 4096;
    bf16x8 af[4], bfr[4];
    #pragma unroll
    for (int mi = 0; mi < 4; mi++)
      af[mi] = *(const bf16x8*)(As + (wm * 64 + mi * 16 + l15) * 32 + quad * 8);
    #pragma unroll
    for (int ni = 0; ni < 4; ni++)
      bfr[ni] = *(const bf16x8*)(Bs + (wn * 64 + ni * 16 + l15) * 32 + quad * 8);
    #pragma unroll
    for (int mi = 0; mi < 4; mi++)
      #pragma unroll
      for (int ni = 0; ni < 4; ni++)
        acc[mi][ni] = __builtin_amdgcn_mfma_f32_16x16x32_bf16(af[mi], bfr[ni], acc[mi][ni], 0, 0, 0);
    pipe_barrier_vm0();
  }

  // epilogue: bias + relu + gate, LDS transpose, then blocked-layout h stores
  bf16* tw0 = S1 + w * 1024;          // per-wave private scratch (buf0 A region)
  bf16* tw1 = S1 + 4096 + w * 1024;   // per-wave private scratch (buf0 B region)
  // this wave's rows live in nb = m0/64 + wm, rows mi*16 + (lane>>2)
  size_t hb = (size_t)pair * 786432 + (size_t)((m0 >> 6) + wm) * 131072;
  const int kgbase = (f0 >> 3) + wn * 8 + (lane & 3) * 2;
  #pragma unroll
  for (int mi = 0; mi < 4; mi++) {
    bf16* tw = (mi & 1) ? tw1 : tw0;
    #pragma unroll
    for (int ni = 0; ni < 4; ni++) {
      float bias = bias_s[wn * 64 + ni * 16 + l15];
      #pragma unroll
      for (int r = 0; r < 4; r++) {
        float v = acc[mi][ni][r] + bias;
        v = fmaxf(v, 0.f) * gate;
        tw[(quad * 4 + r) * 64 + ni * 16 + l15] = __float2bfloat16(v);
      }
    }
    int row = lane >> 2;            // 0..15
    int fpart = (lane & 3) * 16;    // 0,16,32,48
    const uint4* sp = (const uint4*)(tw + row * 64 + fpart);
    uint4 d0 = sp[0];
    uint4 d1 = sp[1];
    bf16* dp = h + hb + (size_t)kgbase * 512 + (mi * 16 + row) * 8;
    *(uint4*)dp = d0;
    *(uint4*)(dp + 512) = d1;
  }
}

// ---------------- GEMM2+pack fused: both experts per block, K=4096 ------------------
// out[b,t,n] += h@We2 (both experts) + gated be2; Abuf[b,n,t] = bf16(out).
// Tile 64(n) x 96(t), BK=64. 2-phase double-buffered staging (R3 schedule).
// K-split waves: wave w computes k-slices kg = 2w+hi with 32x32x16 MFMA; partials
// combined once per block via an LDS reduction. Epilogue: w0 owns n[0,32),
// w1 owns n[32,64); Abuf copy-out by all waves.
// XCD swizzle keeps the 4 t-tiles of a (b,n)-group on one XCD.
#define CT_STRIDE 104
__global__ __launch_bounds__(256, 3) void gemm2_kernel(
    const bf16* __restrict__ h, const bf16* __restrict__ W2B,
    const float* __restrict__ be2, const int* __restrict__ pair_e,
    const float* __restrict__ pair_gate, float* __restrict__ out,
    bf16* __restrict__ Abuf, int layer) {
  // S: 48 KB. Staging: buf b in {0,1}: A = S + b*10240 (4096 els), B = A + 4096
  // (6144 els). Reduction reuses S as float[12288]. Epilogue reuses first
  // 64*CT_STRIDE = 6656 els as the bf16 C-tile.
  __shared__ __align__(16) bf16 S[24576];
  __shared__ float bias_t[96];

  const int tid = threadIdx.x;
  const int w = tid >> 6, lane = tid & 63;
  const int l31 = lane & 31, hi = lane >> 5;
  const int id = blockIdx.x;           // 0..767
  const int u = id & 7;                // XCD (round-robin heuristic)
  const int v = id >> 3;               // 0..95
  const int tt = v & 3;
  const int pn = u + 8 * (v >> 2);     // 0..191
  const int b = pn / 6, nt = pn % 6;
  const int n0 = nt * 64, t0 = tt * 96;

  const int e0 = pair_e[b * 2], e1 = pair_e[b * 2 + 1];
  const float g0 = pair_gate[b * 2], g1 = pair_gate[b * 2 + 1];
  const bf16* Agb0 = h + ((size_t)(b * 2) * 6 + nt) * 131072;
  const bf16* Agb1 = h + ((size_t)(b * 2 + 1) * 6 + nt) * 131072;
  const bf16* Bgb0 = W2B + ((size_t)(layer * E_ + e0) * 4 + tt) * 196608;
  const bf16* Bgb1 = W2B + ((size_t)(layer * E_ + e1) * 4 + tt) * 196608;

  if (tid < 96) {
    int t = t0 + tid;
    bias_t[tid] = (t < T_)
        ? g0 * be2[(layer * E_ + e0) * T_ + t] + g1 * be2[(layer * E_ + e1) * T_ + t]
        : 0.f;
  }

  f32x16 acc[2][3];
  #pragma unroll
  for (int i = 0; i < 2; i++)
    #pragma unroll
    for (int j = 0; j < 3; j++)
      #pragma unroll
      for (int r = 0; r < 16; r++) acc[i][j][r] = 0.f;

  // this wave's k-slice within each BK=64 chunk: kg = 2w + hi  (8 kgs / 4 waves)
  const int aoffA = (2 * w + hi) * 512;
  const int boffB = (2 * w + hi) * 768;

  auto stage2 = [&](int k, int buf) {
    const bf16* Aj = ((k < 32) ? Agb0 : Agb1) + (size_t)(k & 31) * 4096;
    const bf16* Bj = ((k < 32) ? Bgb0 : Bgb1) + (size_t)(k & 31) * 6144;
    bf16* As2 = S + buf * 10240;
    bf16* Bs2 = As2 + 4096;
    #pragma unroll
    for (int i = 0; i < 2; i++)
      async_copy16(Aj + (w * 2 + i) * 512 + lane * 8, As2 + (w * 2 + i) * 512);
    #pragma unroll
    for (int i = 0; i < 3; i++)
      async_copy16(Bj + (w * 3 + i) * 512 + lane * 8, Bs2 + (w * 3 + i) * 512);
  };

  auto compute = [&](int buf) {
    const bf16* As2 = S + buf * 10240;
    const bf16* Bs2 = As2 + 4096;
    bf16x8 af[2], bfr[3];
    #pragma unroll
    for (int mi = 0; mi < 2; mi++)
      af[mi] = *(const bf16x8*)(As2 + aoffA + (mi * 32 + l31) * 8);
    #pragma unroll
    for (int ni = 0; ni < 3; ni++)
      bfr[ni] = *(const bf16x8*)(Bs2 + boffB + (ni * 32 + l31) * 8);
    #pragma unroll
    for (int mi = 0; mi < 2; mi++)
      #pragma unroll
      for (int ni = 0; ni < 3; ni++)
        acc[mi][ni] = __builtin_amdgcn_mfma_f32_32x32x16_bf16(af[mi], bfr[ni], acc[mi][ni], 0, 0, 0);
  };

  stage2(0, 0);
  pipe_barrier_full();

  for (int kk = 0; kk < 64; ++kk) {    // 2 experts x 32 chunks, BK=64
    if (kk < 63) stage2(kk + 1, (kk + 1) & 1);
    compute(kk & 1);
    pipe_barrier_vm0();
  }

  // ---- cross-wave K-reduction through LDS (f32x4 vectorized) ----
  float* R = (float*)S;
  auto dump3 = [&](float* dst, const f32x16 (&a)[3]) {
    #pragma unroll
    for (int ni = 0; ni < 3; ni++)
      #pragma unroll
      for (int rq = 0; rq < 4; rq++) {
        f32x4 t4;
        #pragma unroll
        for (int j = 0; j < 4; j++) t4[j] = a[ni][rq * 4 + j];
        *(f32x4*)(dst + (ni * 4 + rq) * 256 + lane * 4) = t4;
      }
  };
  auto add3 = [&](const float* src, f32x16 (&a)[3]) {
    #pragma unroll
    for (int ni = 0; ni < 3; ni++)
      #pragma unroll
      for (int rq = 0; rq < 4; rq++) {
        f32x4 t4 = *(const f32x4*)(src + (ni * 4 + rq) * 256 + lane * 4);
        #pragma unroll
        for (int j = 0; j < 4; j++) a[ni][rq * 4 + j] += t4[j];
      }
  };

  if (w == 2) { dump3(R, acc[0]); dump3(R + 3072, acc[1]); }
  if (w == 3) { dump3(R + 6144, acc[0]); dump3(R + 9216, acc[1]); }
  __syncthreads();
  if (w == 0) { add3(R, acc[0]); add3(R + 3072, acc[1]); }      // w0 = w0+w2
  if (w == 1) { add3(R + 6144, acc[0]); add3(R + 9216, acc[1]); } // w1 = w1+w3
  __syncthreads();
  if (w == 0) dump3(R, acc[1]);          // w0's mi=1 partial -> region X
  if (w == 1) dump3(R + 3072, acc[0]);   // w1's mi=0 partial -> region Y
  __syncthreads();
  if (w == 0) add3(R + 3072, acc[0]);    // w0: full sum for n[0,32)
  if (w == 1) add3(R, acc[1]);           // w1: full sum for n[32,64)
  __syncthreads();

  // ---- fused pack epilogue: residual merge -> out (fp32) + C-tile -> LDS (bf16)
  auto epi = [&](const f32x16 (&a)[3], int nbase) {
    #pragma unroll
    for (int ni = 0; ni < 3; ni++) {
      #pragma unroll
      for (int r = 0; r < 16; r++) {
        int nloc = nbase + (r & 3) + 8 * (r >> 2) + 4 * hi;  // 32x32 C/D layout
        int tloc = ni * 32 + l31;
        int n = n0 + nloc, t = t0 + tloc;
        float vv = 0.f;
        if (n < N_ && t < T_) {
          size_t q = ((size_t)b * T_ + t) * N_ + n;
          vv = out[q] + a[ni][r] + bias_t[tloc];
          out[q] = vv;
        }
        S[nloc * CT_STRIDE + tloc] = __float2bfloat16(vv);
      }
    }
  };
  if (w == 0) epi(acc[0], 0);
  else if (w == 1) epi(acc[1], 32);
  __syncthreads();

  // transpose-store Abuf rows (coalesced 16B segments); pad cols (t>=T) get zeros
  #pragma unroll
  for (int it = 0; it < 3; ++it) {
    int idx = tid + it * 256;          // < 768 = 64 rows * 12 segs
    int row = idx / 12, seg = idx % 12;
    int t = t0 + seg * 8;
    if (t < TPAD)
      *(uint4*)(Abuf + ((size_t)b * NPAD + n0 + row) * TPAD + t) =
          *(const uint4*)(S + row * CT_STRIDE + seg * 8);
  }
}

// ---------------- projection head: fused two-stage MFMA -----------------------------
#define HS_STRIDE 104  // 96 + 8 pad (208B row stride, 16B-aligned)
__global__ __launch_bounds__(256) void proj_kernel(
    const bf16* __restrict__ Abuf, const bf16* __restrict__ P1T, const float* __restrict__ P1b,
    const bf16* __restrict__ P2T, const float* __restrict__ P2b,
    const float* __restrict__ loss_partial, float* __restrict__ dout) {
  __shared__ __align__(16) bf16 Hs[128 * HS_STRIDE];
  const int tid = threadIdx.x;
  const int w = tid >> 6, lane = tid & 63;
  const int quad = lane >> 4, l15 = lane & 15;
  const int b = blockIdx.y;
  const int m0 = blockIdx.x * 128;

  f32x4 acc1[2][6];
  const f32x4 zero = {0.f, 0.f, 0.f, 0.f};
  #pragma unroll
  for (int i = 0; i < 2; i++)
    #pragma unroll
    for (int j = 0; j < 6; j++) acc1[i][j] = zero;

  const bf16* Arow = Abuf + ((size_t)b * NPAD + m0 + w * 32) * TPAD;
  for (int kk = 0; kk < TPAD / 32; ++kk) {
    bf16x8 af[2], bfr[6];
    #pragma unroll
    for (int mi = 0; mi < 2; mi++)
      af[mi] = *(const bf16x8*)(Arow + (size_t)(mi * 16 + l15) * TPAD + kk * 32 + quad * 8);
    #pragma unroll
    for (int ni = 0; ni < 6; ni++)
      bfr[ni] = *(const bf16x8*)(P1T + (size_t)(ni * 16 + l15) * TPAD + kk * 32 + quad * 8);
    #pragma unroll
    for (int mi = 0; mi < 2; mi++)
      #pragma unroll
      for (int ni = 0; ni < 6; ni++)
        acc1[mi][ni] = __builtin_amdgcn_mfma_f32_16x16x32_bf16(af[mi], bfr[ni], acc1[mi][ni], 0, 0, 0);
  }

  #pragma unroll
  for (int mi = 0; mi < 2; mi++) {
    #pragma unroll
    for (int ni = 0; ni < 6; ni++) {
      float bias = P1b[ni * 16 + l15];
      #pragma unroll
      for (int r = 0; r < 4; r++) {
        float x = acc1[mi][ni][r] + bias;
        float t = 1.f - 2.f / (__expf(2.f * x) + 1.f);
        Hs[(w * 32 + mi * 16 + quad * 4 + r) * HS_STRIDE + ni * 16 + l15] = __float2bfloat16(t);
      }
    }
  }
  __syncthreads();

  #pragma unroll
  for (int half = 0; half < 2; ++half) {
    f32x4 acc2[2][6];
    #pragma unroll
    for (int i = 0; i < 2; i++)
      #pragma unroll
      for (int j = 0; j < 6; j++) acc2[i][j] = zero;

    #pragma unroll
    for (int kk = 0; kk < 3; ++kk) {
      bf16x8 af[2], bfr[6];
      #pragma unroll
      for (int mi = 0; mi < 2; mi++)
        af[mi] = *(const bf16x8*)(Hs + (w * 32 + mi * 16 + l15) * HS_STRIDE + kk * 32 + quad * 8);
      #pragma unroll
      for (int ni = 0; ni < 6; ni++)
        bfr[ni] = *(const bf16x8*)(P2T + (size_t)((half * 6 + ni) * 16 + l15) * P_ + kk * 32 + quad * 8);
      #pragma unroll
      for (int mi = 0; mi < 2; mi++)
        #pragma unroll
        for (int ni = 0; ni < 6; ni++)
          acc2[mi][ni] = __builtin_amdgcn_mfma_f32_16x16x32_bf16(af[mi], bfr[ni], acc2[mi][ni], 0, 0, 0);
    }

    #pragma unroll
    for (int mi = 0; mi < 2; mi++) {
      #pragma unroll
      for (int ni = 0; ni < 6; ni++) {
        int jj = (half * 6 + ni) * 16 + l15;
        float bias = P2b[jj];
        int pout = jj >> 1;
        #pragma unroll
        for (int r = 0; r < 4; r++) {
          int n = m0 + w * 32 + mi * 16 + quad * 4 + r;
          if (n < N_) {
            float s = acc2[mi][ni][r] + bias;
            size_t o = ((size_t)b * P_ + pout) * N_ + n;
            if ((jj & 1) == 0) {
              dout[o] = s;
            } else {
              float sp = (s > 20.f) ? s : log1pf(__expf(s));
              dout[(size_t)B_ * P_ * N_ + 1 + o] = sp + 1e-6f;
            }
          }
        }
      }
    }
  }
  if (b == 0 && blockIdx.x == 0 && tid == 0)
    dout[(size_t)B_ * P_ * N_] = loss_partial[0] + loss_partial[1];
}

// ----------------------------------------------------------------------------------
extern "C" void kernel_launch(void* const* d_in, const int* in_sizes, int n_in,
                              void* d_out, int out_size, void* d_ws, size_t ws_size,
                              hipStream_t stream) {
  const float* x   = (const float*)d_in[0];
  const float* Wg  = (const float*)d_in[11];
  const float* We1 = (const float*)d_in[12];
  const float* be1 = (const float*)d_in[13];
  const float* We2 = (const float*)d_in[14];
  const float* be2 = (const float*)d_in[15];
  const float* P1w = (const float*)d_in[16];
  const float* P1b = (const float*)d_in[17];
  const float* P2w = (const float*)d_in[18];
  const float* P2b = (const float*)d_in[19];

  char* ws = (char*)d_ws;
  size_t off = 0;
  auto alloc = [&](size_t bytes) -> void* {
    void* p = ws + off;
    off += (bytes + 255) & ~(size_t)255;
    return p;
  };
  float* out        = (float*)alloc((size_t)B_ * T_ * N_ * 4);
  bf16*  Abuf       = (bf16*) alloc((size_t)B_ * NPAD * TPAD * 2);
  bf16*  W1T        = (bf16*) alloc((size_t)L_ * E_ * F_ * TPAD * 2);
  bf16*  W2B        = (bf16*) alloc((size_t)L_ * E_ * 4 * 196608 * 2);
  bf16*  P1T        = (bf16*) alloc((size_t)P_ * TPAD * 2);
  bf16*  P2T        = (bf16*) alloc((size_t)2 * P_ * P_ * 2);
  bf16*  h          = (bf16*) alloc((size_t)B_ * 2 * 786432 * 2);
  float* colsum     = (float*)alloc((size_t)B_ * T_ * 4);
  int*   pair_e     = (int*)  alloc(B_ * 2 * 4);
  float* pair_gate  = (float*)alloc(B_ * 2 * 4);
  float* loss_part  = (float*)alloc(2 * 4);
  if (ws_size < off) return;  // workspace too small — bail instead of corrupting

  dim3 tb(32, 8);
  transpose_cast_kernel<<<dim3(11, 64, 8), tb, 0, stream>>>(
      We1, W1T, T_, F_, TPAD, F_, (long long)T_ * F_, (long long)F_ * TPAD);
  repack_w2_kernel<<<dim3(64, 4, 8), 256, 0, stream>>>(We2, W2B);
  transpose_cast_kernel<<<dim3(11, 3, 1), tb, 0, stream>>>(
      P1w, P1T, T_, P_, TPAD, P_, 0, 0);
  transpose_cast_kernel<<<dim3(3, 6, 1), tb, 0, stream>>>(
      P2w, P2T, P_, 2 * P_, P_, 2 * P_, 0, 0);

  revin_kernel<<<dim3(B_, 6), 512, 0, stream>>>(x, out, Abuf);

  for (int l = 0; l < L_; ++l) {
    gate1_kernel<<<dim3(21, B_), 256, 0, stream>>>(out, colsum);
    gate2_kernel<<<1, 128, 0, stream>>>(colsum, Wg, pair_e, pair_gate, loss_part, l);
    gemm1_kernel<<<dim3(16, 3, 64), 256, 0, stream>>>(Abuf, W1T, be1, pair_e, pair_gate, h, l);
    gemm2_kernel<<<768, 256, 0, stream>>>(h, W2B, be2, pair_e, pair_gate, out, Abuf, l);
  }

  proj_kernel<<<dim3(3, B_), 256, 0, stream>>>(Abuf, P1T, P1b, P2T, P2b, loss_part,
                                               (float*)d_out);
}

// Round 7
// 527.723 us; speedup vs baseline: 1.3147x; 1.3147x over previous
//
#include <hip/hip_runtime.h>
#include <hip/hip_bf16.h>
#include <cstdint>
#include <math.h>

#define B_ 32
#define T_ 336
#define N_ 321
#define L_ 2
#define E_ 4
#define F_ 2048
#define P_ 96
#define TPAD 352   // T padded to multiple of 32 (K of GEMM1 / proj stage1)
#define NPAD 384   // N padded to multiple of 128 (M tiles)

typedef __hip_bfloat16 bf16;
typedef __attribute__((ext_vector_type(8))) __bf16 bf16x8;
typedef __attribute__((ext_vector_type(4))) float f32x4;

// h blocked layout: h[pair][nb][kg][row64][8]  (kg = f/8, j = f%8)
//   kg stride 512 els, nb stride 131072 els, pair stride 786432 els.
// W2 blocked layout: W2B[le][tb][kg][row96][8]
//   kg stride 768 els, tb stride 196608 els, le stride 786432 els.
// Both GEMMs use the minimum 2-phase pipeline: double-buffered LDS, stage(k+1)
// issued BEFORE compute(k), one raw s_barrier per K-step with explicit vmcnt(0)
// (no compiler full-drain __syncthreads in the main loop).

__device__ __forceinline__ void async_copy16(const void* g, void* l) {
  __builtin_amdgcn_global_load_lds(
      (__attribute__((address_space(1))) void*)(uintptr_t)g,
      (__attribute__((address_space(3))) void*)(unsigned int)(uintptr_t)l,
      16, 0, 0);
}

__device__ __forceinline__ void pipe_barrier_vm0() {
  asm volatile("s_waitcnt vmcnt(0)" ::: "memory");
  __builtin_amdgcn_s_barrier();
  __builtin_amdgcn_sched_barrier(0);
}

__device__ __forceinline__ void pipe_barrier_full() {
  asm volatile("s_waitcnt vmcnt(0) lgkmcnt(0)" ::: "memory");
  __builtin_amdgcn_s_barrier();
  __builtin_amdgcn_sched_barrier(0);
}

// ---------------- transpose + cast fp32 -> bf16 (K-contiguous operand prep) ----------
__global__ void transpose_cast_kernel(const float* __restrict__ src, bf16* __restrict__ dst,
                                      int R, int C, int Rp, int Cp,
                                      long long sStride, long long dStride) {
  __shared__ float tile[32][33];
  const float* s = src + (size_t)blockIdx.z * sStride;
  bf16* d = dst + (size_t)blockIdx.z * dStride;
  int r0 = blockIdx.x * 32, c0 = blockIdx.y * 32;
  int tx = threadIdx.x, ty = threadIdx.y;
  #pragma unroll
  for (int ii = 0; ii < 4; ii++) {
    int rl = ty * 4 + ii;
    int r = r0 + rl, c = c0 + tx;
    tile[rl][tx] = (r < R && c < C) ? s[(size_t)r * C + c] : 0.f;
  }
  __syncthreads();
  #pragma unroll
  for (int ii = 0; ii < 4; ii++) {
    int cl = ty * 4 + ii;
    int cd = c0 + cl, rd = r0 + tx;
    if (cd < Cp && rd < Rp)
      d[(size_t)cd * Rp + rd] = __float2bfloat16(tile[tx][cl]);
  }
}

// ---------------- We2 -> k-blocked W2B ---------------------------------------------
// grid (F/32, 4, L*E); dst[le][tb][kg][row96][8] = We2[le][f=kg*8+j][t=tb*96+row]
__global__ void repack_w2_kernel(const float* __restrict__ src, bf16* __restrict__ dst) {
  __shared__ float tile[32][96];
  int le = blockIdx.z, tb = blockIdx.y, f0 = blockIdx.x * 32;
  int tid = threadIdx.x;
  const float* s = src + (size_t)le * F_ * T_;
  for (int idx = tid; idx < 32 * 96; idx += 256) {
    int ff = idx / 96, tt = idx % 96;
    int t = tb * 96 + tt;
    tile[ff][tt] = (t < T_) ? s[(size_t)(f0 + ff) * T_ + t] : 0.f;
  }
  __syncthreads();
  bf16* d = dst + ((size_t)le * 4 + tb) * 196608 + (size_t)(f0 >> 3) * 768;
  for (int s2 = tid; s2 < 384; s2 += 256) {
    int kgl = s2 / 96, row = s2 % 96;
    bf16 v[8];
    #pragma unroll
    for (int j = 0; j < 8; j++) v[j] = __float2bfloat16(tile[kgl * 8 + j][row]);
    *(uint4*)(d + (size_t)kgl * 768 + row * 8) = *(const uint4*)v;
  }
}

// ---------------- RevIN + initial pack: x -> out (fp32) and Abuf (bf16, padded) -----
// 512 threads: 64 n-lanes x 8 t-quarters (42 t each). Two passes over x (2nd is
// L3-hot). Abuf transpose staged through a conflict-free LDS uint tile
// (row stride 177 words, gcd(17,32)=1) then linear coalesced copy-out.
__global__ __launch_bounds__(512) void revin_kernel(const float* __restrict__ x,
                                                    float* __restrict__ out,
                                                    bf16* __restrict__ Abuf) {
  __shared__ float red[8][64][2];
  __shared__ float minv[64][2];
  __shared__ unsigned int Lt[64][177];   // 176 used cols (= TPAD/2 uints per row)

  const int b = blockIdx.x;
  const int n0 = blockIdx.y * 64;
  const int tid = threadIdx.x;
  const int nl = tid & 63, tq = tid >> 6;      // tq 0..7
  const int n = n0 + nl;
  const bool valid = (n < N_);
  const float* xp = x + ((size_t)b * T_ * N_ + n) * 3;
  const int tbeg = tq * 42, tend = tbeg + 42;  // 8*42 = 336 = T_

  // pass 1: partial sums over this thread's t-range
  float s1 = 0.f, s2 = 0.f;
  if (valid) {
    for (int t = tbeg; t < tend; t++) {
      float v = xp[(size_t)t * N_ * 3];
      s1 += v; s2 += v * v;
    }
  }
  red[tq][nl][0] = s1; red[tq][nl][1] = s2;
  __syncthreads();
  if (tid < 64) {
    float a = 0.f, c = 0.f;
    #pragma unroll
    for (int q = 0; q < 8; q++) { a += red[q][tid][0]; c += red[q][tid][1]; }
    float mu = a / (float)T_;
    float var = c / (float)T_ - mu * mu;
    minv[tid][0] = mu;
    minv[tid][1] = 1.f / sqrtf(var + 1e-5f);
  }
  // zero the pad cols (t in [336,352) -> uint cols 168..175): 64 rows x 8 cols
  {
    int r = tid >> 3, c = 168 + (tid & 7);
    Lt[r][c] = 0u;
  }
  __syncthreads();

  const float mu = minv[nl][0], inv = minv[nl][1];
  // pass 2: normalize, write out (coalesced), stage packed bf16 pairs into LDS
  for (int t = tbeg; t < tend; t += 2) {
    float v0 = 0.f, v1 = 0.f;
    if (valid) {
      v0 = (xp[(size_t)t * N_ * 3] - mu) * inv;
      v1 = (xp[(size_t)(t + 1) * N_ * 3] - mu) * inv;
      out[((size_t)b * T_ + t) * N_ + n] = v0;
      out[((size_t)b * T_ + t + 1) * N_ + n] = v1;
    }
    bf16 h0 = __float2bfloat16(v0), h1 = __float2bfloat16(v1);
    unsigned int u = (unsigned int)*(unsigned short*)&h0 |
                     ((unsigned int)*(unsigned short*)&h1 << 16);
    Lt[nl][t >> 1] = u;
  }
  __syncthreads();

  // copy-out: 64 rows x 176 uints = 11264 uints, 22 per thread, coalesced
  unsigned int* abase = (unsigned int*)(Abuf + ((size_t)b * NPAD + n0) * TPAD);
  #pragma unroll
  for (int k = 0; k < 22; k++) {
    int idx = tid + k * 512;
    int row = idx / 176, c = idx % 176;
    abase[(size_t)row * (TPAD / 2) + c] = Lt[row][c];
  }
}

// ---------------- gating step 1: colsum[b,t] = sum_n out[b,t,n] ---------------------
__global__ void gate1_kernel(const float* __restrict__ out, float* __restrict__ colsum) {
  int b = blockIdx.y;
  int w = threadIdx.x >> 6, lane = threadIdx.x & 63;
  int t = blockIdx.x * 16 + w * 4;
  #pragma unroll
  for (int i = 0; i < 4; i++, t++) {
    const float* p = out + ((size_t)b * T_ + t) * N_;
    float s = 0.f;
    for (int n = lane; n < N_; n += 64) s += p[n];
    #pragma unroll
    for (int off = 32; off; off >>= 1) s += __shfl_down(s, off);
    if (lane == 0) colsum[b * T_ + t] = s;
  }
}

// ---------------- gating step 2: logits + top-2 + softmax + cv^2 loss ---------------
__global__ void gate2_kernel(const float* __restrict__ colsum, const float* __restrict__ Wg,
                             int* __restrict__ pair_e, float* __restrict__ pair_gate,
                             float* __restrict__ loss_partial, int layer) {
  __shared__ float lg[32][4];
  __shared__ float gates[32][4];
  __shared__ float imp[4];
  int tid = threadIdx.x;
  if (tid < 128) {
    int b = tid >> 2, e = tid & 3;
    float s = 0.f;
    for (int t = 0; t < T_; t++)
      s += colsum[b * T_ + t] * Wg[(layer * T_ + t) * E_ + e];
    lg[b][e] = s / (float)N_;
  }
  __syncthreads();
  if (tid < 32) {
    float v[4];
    #pragma unroll
    for (int e = 0; e < 4; e++) v[e] = lg[tid][e];
    int i0 = 0;
    for (int e = 1; e < 4; e++) if (v[e] > v[i0]) i0 = e;     // lowest index wins ties
    int i1 = -1;
    for (int e = 0; e < 4; e++) {
      if (e == i0) continue;
      if (i1 < 0 || v[e] > v[i1]) i1 = e;
    }
    float ex = expf(v[i1] - v[i0]);
    float g0 = 1.f / (1.f + ex);
    float g1 = ex / (1.f + ex);
    pair_e[tid * 2] = i0; pair_e[tid * 2 + 1] = i1;
    pair_gate[tid * 2] = g0; pair_gate[tid * 2 + 1] = g1;
    #pragma unroll
    for (int e = 0; e < 4; e++) gates[tid][e] = 0.f;
    gates[tid][i0] = g0; gates[tid][i1] = g1;
  }
  __syncthreads();
  if (tid < 4) {
    float s = 0.f;
    for (int bb = 0; bb < 32; bb++) s += gates[bb][tid];
    imp[tid] = s;
  }
  __syncthreads();
  if (tid == 0) {
    float m = (imp[0] + imp[1] + imp[2] + imp[3]) * 0.25f;
    float va = 0.f;
    #pragma unroll
    for (int e = 0; e < 4; e++) { float d = imp[e] - m; va += d * d; }
    va *= 0.25f;
    loss_partial[layer] = 0.01f * (va / (m * m + 1e-10f));
  }
}

// ---------------- GEMM1: h[pair] = gate * relu(Abuf[b] @ We1[l,e] + be1) ------------
// h written in blocked layout (see top). 2-phase pipelined: double-buffered LDS,
// stage(k+1) before compute(k), one barrier per K-step.
__global__ __launch_bounds__(256) void gemm1_kernel(
    const bf16* __restrict__ Abuf, const bf16* __restrict__ W1T,
    const float* __restrict__ be1, const int* __restrict__ pair_e,
    const float* __restrict__ pair_gate, bf16* __restrict__ h, int layer) {
  // buf b: A = S1 + b*8192 (128x32), B = S1 + b*8192 + 4096 (128x32)
  __shared__ __align__(16) bf16 S1[16384];
  __shared__ float bias_s[128];

  const int tid = threadIdx.x;
  const int w = tid >> 6, lane = tid & 63;
  const int pair = blockIdx.z;
  const int b = pair >> 1;
  const int e = pair_e[pair];
  const float gate = pair_gate[pair];
  const int m0 = blockIdx.y * 128;  // n-dim
  const int f0 = blockIdx.x * 128;

  const bf16* Ag = Abuf + (size_t)b * NPAD * TPAD + (size_t)m0 * TPAD;
  const bf16* Bg = W1T + ((size_t)(layer * E_ + e) * F_ + f0) * TPAD;
  if (tid < 128) bias_s[tid] = be1[(size_t)(layer * E_ + e) * F_ + f0 + tid];

  f32x4 acc[4][4];
  const f32x4 zero = {0.f, 0.f, 0.f, 0.f};
  #pragma unroll
  for (int i = 0; i < 4; i++)
    #pragma unroll
    for (int j = 0; j < 4; j++) acc[i][j] = zero;

  const int wm = w >> 1, wn = w & 1;
  const int lrow = lane >> 2;          // 64B-coalesced staging
  const int lkoff = (lane & 3) * 8;
  const int quad = lane >> 4;
  const int l15 = lane & 15;

  auto stage1 = [&](int k, int buf) {
    const int k0 = k * 32;
    bf16* As = S1 + buf * 8192;
    bf16* Bs = As + 4096;
    #pragma unroll
    for (int i = 0; i < 2; i++) {
      int r = (w * 2 + i) * 16 + lrow;
      async_copy16(Ag + (size_t)r * TPAD + k0 + lkoff, As + (w * 2 + i) * 512);
      async_copy16(Bg + (size_t)r * TPAD + k0 + lkoff, Bs + (w * 2 + i) * 512);
    }
  };

  stage1(0, 0);
  pipe_barrier_full();

  for (int kk = 0; kk < TPAD / 32; ++kk) {
    if (kk < TPAD / 32 - 1) stage1(kk + 1, (kk + 1) & 1);
    const bf16* As = S1 + (kk & 1) * 8192;
    const bf16* Bs = As + 4096;
    bf16x8 af[4], bfr[4];
    #pragma unroll
    for (int mi = 0; mi < 4; mi++)
      af[mi] = *(const bf16x8*)(As + (wm * 64 + mi * 16 + l15) * 32 + quad * 8);
    #pragma unroll
    for (int ni = 0; ni < 4; ni++)
      bfr[ni] = *(const bf16x8*)(Bs + (wn * 64 + ni * 16 + l15) * 32 + quad * 8);
    #pragma unroll
    for (int mi = 0; mi < 4; mi++)
      #pragma unroll
      for (int ni = 0; ni < 4; ni++)
        acc[mi][ni] = __builtin_amdgcn_mfma_f32_16x16x32_bf16(af[mi], bfr[ni], acc[mi][ni], 0, 0, 0);
    pipe_barrier_vm0();
  }

  // epilogue: bias + relu + gate, LDS transpose, then blocked-layout h stores
  bf16* tw0 = S1 + w * 1024;          // per-wave private scratch (buf0 A region)
  bf16* tw1 = S1 + 4096 + w * 1024;   // per-wave private scratch (buf0 B region)
  // this wave's rows live in nb = m0/64 + wm, rows mi*16 + (lane>>2)
  size_t hb = (size_t)pair * 786432 + (size_t)((m0 >> 6) + wm) * 131072;
  const int kgbase = (f0 >> 3) + wn * 8 + (lane & 3) * 2;
  #pragma unroll
  for (int mi = 0; mi < 4; mi++) {
    bf16* tw = (mi & 1) ? tw1 : tw0;
    #pragma unroll
    for (int ni = 0; ni < 4; ni++) {
      float bias = bias_s[wn * 64 + ni * 16 + l15];
      #pragma unroll
      for (int r = 0; r < 4; r++) {
        float v = acc[mi][ni][r] + bias;
        v = fmaxf(v, 0.f) * gate;
        tw[(quad * 4 + r) * 64 + ni * 16 + l15] = __float2bfloat16(v);
      }
    }
    int row = lane >> 2;            // 0..15
    int fpart = (lane & 3) * 16;    // 0,16,32,48
    const uint4* sp = (const uint4*)(tw + row * 64 + fpart);
    uint4 d0 = sp[0];
    uint4 d1 = sp[1];
    bf16* dp = h + hb + (size_t)kgbase * 512 + (mi * 16 + row) * 8;
    *(uint4*)dp = d0;
    *(uint4*)(dp + 512) = d1;
  }
}

// ---------------- GEMM2+pack fused: both experts per block, K=4096 ------------------
// out[b,t,n] += h@We2 (both experts) + gated be2; Abuf[b,n,t] = bf16(out).
// Tile 64(n) x 96(t), BK=64; A/B staged as LINEAR contiguous chunks (blocked layouts)
// into a double-buffered LDS region, 2-phase pipelined (stage(k+1) under compute(k)),
// one raw barrier + vmcnt(0) per K-step.
// XCD swizzle keeps the 4 t-tiles of a (b,n)-group on one XCD.
#define CT_STRIDE 104
__global__ __launch_bounds__(256) void gemm2_kernel(
    const bf16* __restrict__ h, const bf16* __restrict__ W2B,
    const float* __restrict__ be2, const int* __restrict__ pair_e,
    const float* __restrict__ pair_gate, float* __restrict__ out,
    bf16* __restrict__ Abuf, int layer) {
  // buf b: A = S + b*10240 (4096 els), B = A + 4096 (6144 els).
  // epilogue reuses first 64*CT_STRIDE = 6656 els as bf16 C-tile.
  __shared__ __align__(16) bf16 S[20480];
  __shared__ float bias_t[96];

  const int tid = threadIdx.x;
  const int w = tid >> 6, lane = tid & 63;
  const int id = blockIdx.x;           // 0..767
  const int u = id & 7;                // XCD (round-robin heuristic)
  const int v = id >> 3;               // 0..95
  const int tt = v & 3;
  const int pn = u + 8 * (v >> 2);     // 0..191
  const int b = pn / 6, nt = pn % 6;
  const int n0 = nt * 64, t0 = tt * 96;

  const int e0 = pair_e[b * 2], e1 = pair_e[b * 2 + 1];
  const float g0 = pair_gate[b * 2], g1 = pair_gate[b * 2 + 1];
  const bf16* Agb0 = h + ((size_t)(b * 2) * 6 + nt) * 131072;
  const bf16* Agb1 = h + ((size_t)(b * 2 + 1) * 6 + nt) * 131072;
  const bf16* Bgb0 = W2B + ((size_t)(layer * E_ + e0) * 4 + tt) * 196608;
  const bf16* Bgb1 = W2B + ((size_t)(layer * E_ + e1) * 4 + tt) * 196608;
  const int quad = lane >> 4, l15 = lane & 15;
  const int wm = w >> 1, wt = w & 1;   // wave tile: 32(n) x 48(t)

  if (tid < 96) {
    int t = t0 + tid;
    bias_t[tid] = (t < T_)
        ? g0 * be2[(layer * E_ + e0) * T_ + t] + g1 * be2[(layer * E_ + e1) * T_ + t]
        : 0.f;
  }

  f32x4 acc[2][3];
  const f32x4 zero = {0.f, 0.f, 0.f, 0.f};
  #pragma unroll
  for (int i = 0; i < 2; i++)
    #pragma unroll
    for (int jj = 0; jj < 3; jj++) acc[i][jj] = zero;

  auto stage2 = [&](int k, int buf) {
    const bf16* Aj = ((k < 32) ? Agb0 : Agb1) + (size_t)(k & 31) * 4096;
    const bf16* Bj = ((k < 32) ? Bgb0 : Bgb1) + (size_t)(k & 31) * 6144;
    bf16* As2 = S + buf * 10240;
    bf16* Bs2 = As2 + 4096;
    #pragma unroll
    for (int i = 0; i < 2; i++)
      async_copy16(Aj + (w * 2 + i) * 512 + lane * 8, As2 + (w * 2 + i) * 512);
    #pragma unroll
    for (int i = 0; i < 3; i++)
      async_copy16(Bj + (w * 3 + i) * 512 + lane * 8, Bs2 + (w * 3 + i) * 512);
  };

  stage2(0, 0);
  pipe_barrier_full();

  for (int kk = 0; kk < 64; ++kk) {    // 2 experts x 32 chunks, BK=64
    if (kk < 63) stage2(kk + 1, (kk + 1) & 1);
    const bf16* As2 = S + (kk & 1) * 10240;
    const bf16* Bs2 = As2 + 4096;
    #pragma unroll
    for (int w32 = 0; w32 < 2; w32++) {
      const int kg = w32 * 4 + quad;
      bf16x8 af[2], bfr[3];
      #pragma unroll
      for (int mi = 0; mi < 2; mi++)
        af[mi] = *(const bf16x8*)(As2 + kg * 512 + (wm * 32 + mi * 16 + l15) * 8);
      #pragma unroll
      for (int ni = 0; ni < 3; ni++)
        bfr[ni] = *(const bf16x8*)(Bs2 + kg * 768 + (wt * 48 + ni * 16 + l15) * 8);
      #pragma unroll
      for (int mi = 0; mi < 2; mi++)
        #pragma unroll
        for (int ni = 0; ni < 3; ni++)
          acc[mi][ni] = __builtin_amdgcn_mfma_f32_16x16x32_bf16(af[mi], bfr[ni], acc[mi][ni], 0, 0, 0);
    }
    pipe_barrier_vm0();
  }

  // ---- fused pack epilogue: residual merge -> out (fp32) + C-tile -> LDS (bf16)
  #pragma unroll
  for (int mi = 0; mi < 2; mi++) {
    #pragma unroll
    for (int ni = 0; ni < 3; ni++) {
      int nloc_b = wm * 32 + mi * 16 + quad * 4;
      int tloc = wt * 48 + ni * 16 + l15;
      int t = t0 + tloc;
      #pragma unroll
      for (int r = 0; r < 4; r++) {
        int nloc = nloc_b + r;
        int n = n0 + nloc;
        float vv = 0.f;
        if (n < N_ && t < T_) {
          size_t q = ((size_t)b * T_ + t) * N_ + n;
          vv = out[q] + acc[mi][ni][r] + bias_t[tloc];
          out[q] = vv;
        }
        S[nloc * CT_STRIDE + tloc] = __float2bfloat16(vv);
      }
    }
  }
  __syncthreads();
  // transpose-store Abuf rows (coalesced 16B segments); pad cols (t>=T) get zeros
  #pragma unroll
  for (int it = 0; it < 3; ++it) {
    int idx = tid + it * 256;          // < 768 = 64 rows * 12 segs
    int row = idx / 12, seg = idx % 12;
    int t = t0 + seg * 8;
    if (t < TPAD)
      *(uint4*)(Abuf + ((size_t)b * NPAD + n0 + row) * TPAD + t) =
          *(const uint4*)(S + row * CT_STRIDE + seg * 8);
  }
}

// ---------------- projection head: fused two-stage MFMA -----------------------------
// Retiled vs R3: 64 rows/block, grid (6,B) = 192 blocks (was 128 rows, 96 blocks).
// Each wave owns ONE 16-row MFMA strip (was two) -> half the dependent-chain depth,
// 2x the CU coverage. Math and layouts unchanged.
#define HS_STRIDE 104  // 96 + 8 pad (208B row stride, 16B-aligned)
__global__ __launch_bounds__(256) void proj_kernel(
    const bf16* __restrict__ Abuf, const bf16* __restrict__ P1T, const float* __restrict__ P1b,
    const bf16* __restrict__ P2T, const float* __restrict__ P2b,
    const float* __restrict__ loss_partial, float* __restrict__ dout) {
  __shared__ __align__(16) bf16 Hs[64 * HS_STRIDE];
  const int tid = threadIdx.x;
  const int w = tid >> 6, lane = tid & 63;
  const int quad = lane >> 4, l15 = lane & 15;
  const int b = blockIdx.y;
  const int m0 = blockIdx.x * 64;
  const int row = w * 16;              // wave's row strip within the 64-row tile

  f32x4 acc1[6];
  const f32x4 zero = {0.f, 0.f, 0.f, 0.f};
  #pragma unroll
  for (int j = 0; j < 6; j++) acc1[j] = zero;

  const bf16* Arow = Abuf + ((size_t)b * NPAD + m0 + row) * TPAD;
  for (int kk = 0; kk < TPAD / 32; ++kk) {
    bf16x8 af, bfr[6];
    af = *(const bf16x8*)(Arow + (size_t)l15 * TPAD + kk * 32 + quad * 8);
    #pragma unroll
    for (int ni = 0; ni < 6; ni++)
      bfr[ni] = *(const bf16x8*)(P1T + (size_t)(ni * 16 + l15) * TPAD + kk * 32 + quad * 8);
    #pragma unroll
    for (int ni = 0; ni < 6; ni++)
      acc1[ni] = __builtin_amdgcn_mfma_f32_16x16x32_bf16(af, bfr[ni], acc1[ni], 0, 0, 0);
  }

  #pragma unroll
  for (int ni = 0; ni < 6; ni++) {
    float bias = P1b[ni * 16 + l15];
    #pragma unroll
    for (int r = 0; r < 4; r++) {
      float x = acc1[ni][r] + bias;
      float t = 1.f - 2.f / (__expf(2.f * x) + 1.f);
      Hs[(row + quad * 4 + r) * HS_STRIDE + ni * 16 + l15] = __float2bfloat16(t);
    }
  }
  __syncthreads();

  #pragma unroll
  for (int half = 0; half < 2; ++half) {
    f32x4 acc2[6];
    #pragma unroll
    for (int j = 0; j < 6; j++) acc2[j] = zero;

    #pragma unroll
    for (int kk = 0; kk < 3; ++kk) {
      bf16x8 af, bfr[6];
      af = *(const bf16x8*)(Hs + (row + l15) * HS_STRIDE + kk * 32 + quad * 8);
      #pragma unroll
      for (int ni = 0; ni < 6; ni++)
        bfr[ni] = *(const bf16x8*)(P2T + (size_t)((half * 6 + ni) * 16 + l15) * P_ + kk * 32 + quad * 8);
      #pragma unroll
      for (int ni = 0; ni < 6; ni++)
        acc2[ni] = __builtin_amdgcn_mfma_f32_16x16x32_bf16(af, bfr[ni], acc2[ni], 0, 0, 0);
    }

    #pragma unroll
    for (int ni = 0; ni < 6; ni++) {
      int jj = (half * 6 + ni) * 16 + l15;
      float bias = P2b[jj];
      int pout = jj >> 1;
      #pragma unroll
      for (int r = 0; r < 4; r++) {
        int n = m0 + row + quad * 4 + r;
        if (n < N_) {
          float s = acc2[ni][r] + bias;
          size_t o = ((size_t)b * P_ + pout) * N_ + n;
          if ((jj & 1) == 0) {
            dout[o] = s;
          } else {
            float sp = (s > 20.f) ? s : log1pf(__expf(s));
            dout[(size_t)B_ * P_ * N_ + 1 + o] = sp + 1e-6f;
          }
        }
      }
    }
  }
  if (b == 0 && blockIdx.x == 0 && tid == 0)
    dout[(size_t)B_ * P_ * N_] = loss_partial[0] + loss_partial[1];
}

// ----------------------------------------------------------------------------------
extern "C" void kernel_launch(void* const* d_in, const int* in_sizes, int n_in,
                              void* d_out, int out_size, void* d_ws, size_t ws_size,
                              hipStream_t stream) {
  const float* x   = (const float*)d_in[0];
  const float* Wg  = (const float*)d_in[11];
  const float* We1 = (const float*)d_in[12];
  const float* be1 = (const float*)d_in[13];
  const float* We2 = (const float*)d_in[14];
  const float* be2 = (const float*)d_in[15];
  const float* P1w = (const float*)d_in[16];
  const float* P1b = (const float*)d_in[17];
  const float* P2w = (const float*)d_in[18];
  const float* P2b = (const float*)d_in[19];

  char* ws = (char*)d_ws;
  size_t off = 0;
  auto alloc = [&](size_t bytes) -> void* {
    void* p = ws + off;
    off += (bytes + 255) & ~(size_t)255;
    return p;
  };
  float* out        = (float*)alloc((size_t)B_ * T_ * N_ * 4);
  bf16*  Abuf       = (bf16*) alloc((size_t)B_ * NPAD * TPAD * 2);
  bf16*  W1T        = (bf16*) alloc((size_t)L_ * E_ * F_ * TPAD * 2);
  bf16*  W2B        = (bf16*) alloc((size_t)L_ * E_ * 4 * 196608 * 2);
  bf16*  P1T        = (bf16*) alloc((size_t)P_ * TPAD * 2);
  bf16*  P2T        = (bf16*) alloc((size_t)2 * P_ * P_ * 2);
  bf16*  h          = (bf16*) alloc((size_t)B_ * 2 * 786432 * 2);
  float* colsum     = (float*)alloc((size_t)B_ * T_ * 4);
  int*   pair_e     = (int*)  alloc(B_ * 2 * 4);
  float* pair_gate  = (float*)alloc(B_ * 2 * 4);
  float* loss_part  = (float*)alloc(2 * 4);
  if (ws_size < off) return;  // workspace too small — bail instead of corrupting

  dim3 tb(32, 8);
  transpose_cast_kernel<<<dim3(11, 64, 8), tb, 0, stream>>>(
      We1, W1T, T_, F_, TPAD, F_, (long long)T_ * F_, (long long)F_ * TPAD);
  repack_w2_kernel<<<dim3(64, 4, 8), 256, 0, stream>>>(We2, W2B);
  transpose_cast_kernel<<<dim3(11, 3, 1), tb, 0, stream>>>(
      P1w, P1T, T_, P_, TPAD, P_, 0, 0);
  transpose_cast_kernel<<<dim3(3, 6, 1), tb, 0, stream>>>(
      P2w, P2T, P_, 2 * P_, P_, 2 * P_, 0, 0);

  revin_kernel<<<dim3(B_, 6), 512, 0, stream>>>(x, out, Abuf);

  for (int l = 0; l < L_; ++l) {
    gate1_kernel<<<dim3(21, B_), 256, 0, stream>>>(out, colsum);
    gate2_kernel<<<1, 128, 0, stream>>>(colsum, Wg, pair_e, pair_gate, loss_part, l);
    gemm1_kernel<<<dim3(16, 3, 64), 256, 0, stream>>>(Abuf, W1T, be1, pair_e, pair_gate, h, l);
    gemm2_kernel<<<768, 256, 0, stream>>>(h, W2B, be2, pair_e, pair_gate, out, Abuf, l);
  }

  proj_kernel<<<dim3(6, B_), 256, 0, stream>>>(Abuf, P1T, P1b, P2T, P2b, loss_part,
                                               (float*)d_out);
}

// Round 8
// 504.370 us; speedup vs baseline: 1.3755x; 1.0463x over previous
//
#include <hip/hip_runtime.h>
#include <hip/hip_bf16.h>
#include <cstdint>
#include <math.h>

#define B_ 32
#define T_ 336
#define N_ 321
#define L_ 2
#define E_ 4
#define F_ 2048
#define P_ 96
#define TPAD 352   // T padded to multiple of 32 (K of GEMM1 / proj stage1)
#define NPAD 384   // N padded to multiple of 128 (M tiles)

typedef __hip_bfloat16 bf16;
typedef __attribute__((ext_vector_type(8))) __bf16 bf16x8;
typedef __attribute__((ext_vector_type(4))) float f32x4;

// h blocked layout: h[pair][nb][kg][row64][8]  (kg = f/8, j = f%8)
//   kg stride 512 els, nb stride 131072 els, pair stride 786432 els.
// W2 blocked layout: W2B[le][tb][kg][row96][8]
//   kg stride 768 els, tb stride 196608 els, le stride 786432 els.
// gemm2: asymmetric-depth pipeline — A (h, HBM-latency stream) triple-buffered
// and prefetched 2 K-steps ahead; B (W2B, L2-resident) double-buffered 1 ahead.
// Per K-step: issue B(k+1), issue A(k+2), compute(k), s_waitcnt vmcnt(2)
// (A(k+2) stays in flight), s_barrier. vmcnt never drains to 0 in the loop.
// LDS 48KB -> 3 blocks/CU retained (R4's 62KB/2-block failure mode avoided).

__device__ __forceinline__ void async_copy16(const void* g, void* l) {
  __builtin_amdgcn_global_load_lds(
      (__attribute__((address_space(1))) void*)(uintptr_t)g,
      (__attribute__((address_space(3))) void*)(unsigned int)(uintptr_t)l,
      16, 0, 0);
}

__device__ __forceinline__ void pipe_barrier_vm0() {
  asm volatile("s_waitcnt vmcnt(0)" ::: "memory");
  __builtin_amdgcn_s_barrier();
  __builtin_amdgcn_sched_barrier(0);
}

__device__ __forceinline__ void pipe_barrier_full() {
  asm volatile("s_waitcnt vmcnt(0) lgkmcnt(0)" ::: "memory");
  __builtin_amdgcn_s_barrier();
  __builtin_amdgcn_sched_barrier(0);
}

#define G2_WAITN(N)                                         \
  do {                                                      \
    asm volatile("s_waitcnt vmcnt(" #N ")" ::: "memory");   \
    __builtin_amdgcn_s_barrier();                           \
    __builtin_amdgcn_sched_barrier(0);                      \
  } while (0)

// ---------------- transpose + cast fp32 -> bf16 (K-contiguous operand prep) ----------
__global__ void transpose_cast_kernel(const float* __restrict__ src, bf16* __restrict__ dst,
                                      int R, int C, int Rp, int Cp,
                                      long long sStride, long long dStride) {
  __shared__ float tile[32][33];
  const float* s = src + (size_t)blockIdx.z * sStride;
  bf16* d = dst + (size_t)blockIdx.z * dStride;
  int r0 = blockIdx.x * 32, c0 = blockIdx.y * 32;
  int tx = threadIdx.x, ty = threadIdx.y;
  #pragma unroll
  for (int ii = 0; ii < 4; ii++) {
    int rl = ty * 4 + ii;
    int r = r0 + rl, c = c0 + tx;
    tile[rl][tx] = (r < R && c < C) ? s[(size_t)r * C + c] : 0.f;
  }
  __syncthreads();
  #pragma unroll
  for (int ii = 0; ii < 4; ii++) {
    int cl = ty * 4 + ii;
    int cd = c0 + cl, rd = r0 + tx;
    if (cd < Cp && rd < Rp)
      d[(size_t)cd * Rp + rd] = __float2bfloat16(tile[tx][cl]);
  }
}

// ---------------- We2 -> k-blocked W2B ---------------------------------------------
// grid (F/32, 4, L*E); dst[le][tb][kg][row96][8] = We2[le][f=kg*8+j][t=tb*96+row]
__global__ void repack_w2_kernel(const float* __restrict__ src, bf16* __restrict__ dst) {
  __shared__ float tile[32][96];
  int le = blockIdx.z, tb = blockIdx.y, f0 = blockIdx.x * 32;
  int tid = threadIdx.x;
  const float* s = src + (size_t)le * F_ * T_;
  for (int idx = tid; idx < 32 * 96; idx += 256) {
    int ff = idx / 96, tt = idx % 96;
    int t = tb * 96 + tt;
    tile[ff][tt] = (t < T_) ? s[(size_t)(f0 + ff) * T_ + t] : 0.f;
  }
  __syncthreads();
  bf16* d = dst + ((size_t)le * 4 + tb) * 196608 + (size_t)(f0 >> 3) * 768;
  for (int s2 = tid; s2 < 384; s2 += 256) {
    int kgl = s2 / 96, row = s2 % 96;
    bf16 v[8];
    #pragma unroll
    for (int j = 0; j < 8; j++) v[j] = __float2bfloat16(tile[kgl * 8 + j][row]);
    *(uint4*)(d + (size_t)kgl * 768 + row * 8) = *(const uint4*)v;
  }
}

// ---------------- RevIN + initial pack: x -> out (fp32) and Abuf (bf16, padded) -----
// 512 threads: 64 n-lanes x 8 t-quarters (42 t each). Two passes over x (2nd is
// L3-hot). Abuf transpose staged through a conflict-free LDS uint tile
// (row stride 177 words, gcd(17,32)=1) then linear coalesced copy-out.
__global__ __launch_bounds__(512) void revin_kernel(const float* __restrict__ x,
                                                    float* __restrict__ out,
                                                    bf16* __restrict__ Abuf) {
  __shared__ float red[8][64][2];
  __shared__ float minv[64][2];
  __shared__ unsigned int Lt[64][177];   // 176 used cols (= TPAD/2 uints per row)

  const int b = blockIdx.x;
  const int n0 = blockIdx.y * 64;
  const int tid = threadIdx.x;
  const int nl = tid & 63, tq = tid >> 6;      // tq 0..7
  const int n = n0 + nl;
  const bool valid = (n < N_);
  const float* xp = x + ((size_t)b * T_ * N_ + n) * 3;
  const int tbeg = tq * 42, tend = tbeg + 42;  // 8*42 = 336 = T_

  // pass 1: partial sums over this thread's t-range
  float s1 = 0.f, s2 = 0.f;
  if (valid) {
    for (int t = tbeg; t < tend; t++) {
      float v = xp[(size_t)t * N_ * 3];
      s1 += v; s2 += v * v;
    }
  }
  red[tq][nl][0] = s1; red[tq][nl][1] = s2;
  __syncthreads();
  if (tid < 64) {
    float a = 0.f, c = 0.f;
    #pragma unroll
    for (int q = 0; q < 8; q++) { a += red[q][tid][0]; c += red[q][tid][1]; }
    float mu = a / (float)T_;
    float var = c / (float)T_ - mu * mu;
    minv[tid][0] = mu;
    minv[tid][1] = 1.f / sqrtf(var + 1e-5f);
  }
  // zero the pad cols (t in [336,352) -> uint cols 168..175): 64 rows x 8 cols
  {
    int r = tid >> 3, c = 168 + (tid & 7);
    Lt[r][c] = 0u;
  }
  __syncthreads();

  const float mu = minv[nl][0], inv = minv[nl][1];
  // pass 2: normalize, write out (coalesced), stage packed bf16 pairs into LDS
  for (int t = tbeg; t < tend; t += 2) {
    float v0 = 0.f, v1 = 0.f;
    if (valid) {
      v0 = (xp[(size_t)t * N_ * 3] - mu) * inv;
      v1 = (xp[(size_t)(t + 1) * N_ * 3] - mu) * inv;
      out[((size_t)b * T_ + t) * N_ + n] = v0;
      out[((size_t)b * T_ + t + 1) * N_ + n] = v1;
    }
    bf16 h0 = __float2bfloat16(v0), h1 = __float2bfloat16(v1);
    unsigned int u = (unsigned int)*(unsigned short*)&h0 |
                     ((unsigned int)*(unsigned short*)&h1 << 16);
    Lt[nl][t >> 1] = u;
  }
  __syncthreads();

  // copy-out: 64 rows x 176 uints = 11264 uints, 22 per thread, coalesced
  unsigned int* abase = (unsigned int*)(Abuf + ((size_t)b * NPAD + n0) * TPAD);
  #pragma unroll
  for (int k = 0; k < 22; k++) {
    int idx = tid + k * 512;
    int row = idx / 176, c = idx % 176;
    abase[(size_t)row * (TPAD / 2) + c] = Lt[row][c];
  }
}

// ---------------- gating step 1: colsum[b,t] = sum_n out[b,t,n] ---------------------
__global__ void gate1_kernel(const float* __restrict__ out, float* __restrict__ colsum) {
  int b = blockIdx.y;
  int w = threadIdx.x >> 6, lane = threadIdx.x & 63;
  int t = blockIdx.x * 16 + w * 4;
  #pragma unroll
  for (int i = 0; i < 4; i++, t++) {
    const float* p = out + ((size_t)b * T_ + t) * N_;
    float s = 0.f;
    for (int n = lane; n < N_; n += 64) s += p[n];
    #pragma unroll
    for (int off = 32; off; off >>= 1) s += __shfl_down(s, off);
    if (lane == 0) colsum[b * T_ + t] = s;
  }
}

// ---------------- gating step 2: logits + top-2 + softmax + cv^2 loss ---------------
__global__ void gate2_kernel(const float* __restrict__ colsum, const float* __restrict__ Wg,
                             int* __restrict__ pair_e, float* __restrict__ pair_gate,
                             float* __restrict__ loss_partial, int layer) {
  __shared__ float lg[32][4];
  __shared__ float gates[32][4];
  __shared__ float imp[4];
  int tid = threadIdx.x;
  if (tid < 128) {
    int b = tid >> 2, e = tid & 3;
    float s = 0.f;
    for (int t = 0; t < T_; t++)
      s += colsum[b * T_ + t] * Wg[(layer * T_ + t) * E_ + e];
    lg[b][e] = s / (float)N_;
  }
  __syncthreads();
  if (tid < 32) {
    float v[4];
    #pragma unroll
    for (int e = 0; e < 4; e++) v[e] = lg[tid][e];
    int i0 = 0;
    for (int e = 1; e < 4; e++) if (v[e] > v[i0]) i0 = e;     // lowest index wins ties
    int i1 = -1;
    for (int e = 0; e < 4; e++) {
      if (e == i0) continue;
      if (i1 < 0 || v[e] > v[i1]) i1 = e;
    }
    float ex = expf(v[i1] - v[i0]);
    float g0 = 1.f / (1.f + ex);
    float g1 = ex / (1.f + ex);
    pair_e[tid * 2] = i0; pair_e[tid * 2 + 1] = i1;
    pair_gate[tid * 2] = g0; pair_gate[tid * 2 + 1] = g1;
    #pragma unroll
    for (int e = 0; e < 4; e++) gates[tid][e] = 0.f;
    gates[tid][i0] = g0; gates[tid][i1] = g1;
  }
  __syncthreads();
  if (tid < 4) {
    float s = 0.f;
    for (int bb = 0; bb < 32; bb++) s += gates[bb][tid];
    imp[tid] = s;
  }
  __syncthreads();
  if (tid == 0) {
    float m = (imp[0] + imp[1] + imp[2] + imp[3]) * 0.25f;
    float va = 0.f;
    #pragma unroll
    for (int e = 0; e < 4; e++) { float d = imp[e] - m; va += d * d; }
    va *= 0.25f;
    loss_partial[layer] = 0.01f * (va / (m * m + 1e-10f));
  }
}

// ---------------- GEMM1: h[pair] = gate * relu(Abuf[b] @ We1[l,e] + be1) ------------
// h written in blocked layout (see top). 2-phase pipelined: double-buffered LDS,
// stage(k+1) before compute(k), one barrier per K-step.
__global__ __launch_bounds__(256) void gemm1_kernel(
    const bf16* __restrict__ Abuf, const bf16* __restrict__ W1T,
    const float* __restrict__ be1, const int* __restrict__ pair_e,
    const float* __restrict__ pair_gate, bf16* __restrict__ h, int layer) {
  // buf b: A = S1 + b*8192 (128x32), B = S1 + b*8192 + 4096 (128x32)
  __shared__ __align__(16) bf16 S1[16384];
  __shared__ float bias_s[128];

  const int tid = threadIdx.x;
  const int w = tid >> 6, lane = tid & 63;
  const int pair = blockIdx.z;
  const int b = pair >> 1;
  const int e = pair_e[pair];
  const float gate = pair_gate[pair];
  const int m0 = blockIdx.y * 128;  // n-dim
  const int f0 = blockIdx.x * 128;

  const bf16* Ag = Abuf + (size_t)b * NPAD * TPAD + (size_t)m0 * TPAD;
  const bf16* Bg = W1T + ((size_t)(layer * E_ + e) * F_ + f0) * TPAD;
  if (tid < 128) bias_s[tid] = be1[(size_t)(layer * E_ + e) * F_ + f0 + tid];

  f32x4 acc[4][4];
  const f32x4 zero = {0.f, 0.f, 0.f, 0.f};
  #pragma unroll
  for (int i = 0; i < 4; i++)
    #pragma unroll
    for (int j = 0; j < 4; j++) acc[i][j] = zero;

  const int wm = w >> 1, wn = w & 1;
  const int lrow = lane >> 2;          // 64B-coalesced staging
  const int lkoff = (lane & 3) * 8;
  const int quad = lane >> 4;
  const int l15 = lane & 15;

  auto stage1 = [&](int k, int buf) {
    const int k0 = k * 32;
    bf16* As = S1 + buf * 8192;
    bf16* Bs = As + 4096;
    #pragma unroll
    for (int i = 0; i < 2; i++) {
      int r = (w * 2 + i) * 16 + lrow;
      async_copy16(Ag + (size_t)r * TPAD + k0 + lkoff, As + (w * 2 + i) * 512);
      async_copy16(Bg + (size_t)r * TPAD + k0 + lkoff, Bs + (w * 2 + i) * 512);
    }
  };

  stage1(0, 0);
  pipe_barrier_full();

  for (int kk = 0; kk < TPAD / 32; ++kk) {
    if (kk < TPAD / 32 - 1) stage1(kk + 1, (kk + 1) & 1);
    const bf16* As = S1 + (kk & 1) * 8192;
    const bf16* Bs = As + 4096;
    bf16x8 af[4], bfr[4];
    #pragma unroll
    for (int mi = 0; mi < 4; mi++)
      af[mi] = *(const bf16x8*)(As + (wm * 64 + mi * 16 + l15) * 32 + quad * 8);
    #pragma unroll
    for (int ni = 0; ni < 4; ni++)
      bfr[ni] = *(const bf16x8*)(Bs + (wn * 64 + ni * 16 + l15) * 32 + quad * 8);
    #pragma unroll
    for (int mi = 0; mi < 4; mi++)
      #pragma unroll
      for (int ni = 0; ni < 4; ni++)
        acc[mi][ni] = __builtin_amdgcn_mfma_f32_16x16x32_bf16(af[mi], bfr[ni], acc[mi][ni], 0, 0, 0);
    pipe_barrier_vm0();
  }

  // epilogue: bias + relu + gate, LDS transpose, then blocked-layout h stores
  bf16* tw0 = S1 + w * 1024;          // per-wave private scratch (buf0 A region)
  bf16* tw1 = S1 + 4096 + w * 1024;   // per-wave private scratch (buf0 B region)
  // this wave's rows live in nb = m0/64 + wm, rows mi*16 + (lane>>2)
  size_t hb = (size_t)pair * 786432 + (size_t)((m0 >> 6) + wm) * 131072;
  const int kgbase = (f0 >> 3) + wn * 8 + (lane & 3) * 2;
  #pragma unroll
  for (int mi = 0; mi < 4; mi++) {
    bf16* tw = (mi & 1) ? tw1 : tw0;
    #pragma unroll
    for (int ni = 0; ni < 4; ni++) {
      float bias = bias_s[wn * 64 + ni * 16 + l15];
      #pragma unroll
      for (int r = 0; r < 4; r++) {
        float v = acc[mi][ni][r] + bias;
        v = fmaxf(v, 0.f) * gate;
        tw[(quad * 4 + r) * 64 + ni * 16 + l15] = __float2bfloat16(v);
      }
    }
    int row = lane >> 2;            // 0..15
    int fpart = (lane & 3) * 16;    // 0,16,32,48
    const uint4* sp = (const uint4*)(tw + row * 64 + fpart);
    uint4 d0 = sp[0];
    uint4 d1 = sp[1];
    bf16* dp = h + hb + (size_t)kgbase * 512 + (mi * 16 + row) * 8;
    *(uint4*)dp = d0;
    *(uint4*)(dp + 512) = d1;
  }
}

// ---------------- GEMM2+pack fused: both experts per block, K=4096 ------------------
// out[b,t,n] += h@We2 (both experts) + gated be2; Abuf[b,n,t] = bf16(out).
// Tile 64(n) x 96(t), BK=64. A triple-buffered (2-ahead), B double-buffered
// (1-ahead), counted vmcnt(2) at the per-step barrier (see file-top comment).
// XCD swizzle keeps the 4 t-tiles of a (b,n)-group on one XCD.
#define CT_STRIDE 104
__global__ __launch_bounds__(256) void gemm2_kernel(
    const bf16* __restrict__ h, const bf16* __restrict__ W2B,
    const float* __restrict__ be2, const int* __restrict__ pair_e,
    const float* __restrict__ pair_gate, float* __restrict__ out,
    bf16* __restrict__ Abuf, int layer) {
  // S layout (els): A0@0 A1@4096 A2@8192 | B0@12288 B1@18432 | end 24576 (48KB).
  // epilogue reuses first 64*CT_STRIDE = 6656 els as bf16 C-tile.
  __shared__ __align__(16) bf16 S[24576];
  __shared__ float bias_t[96];

  const int tid = threadIdx.x;
  const int w = tid >> 6, lane = tid & 63;
  const int id = blockIdx.x;           // 0..767
  const int u = id & 7;                // XCD (round-robin heuristic)
  const int v = id >> 3;               // 0..95
  const int tt = v & 3;
  const int pn = u + 8 * (v >> 2);     // 0..191
  const int b = pn / 6, nt = pn % 6;
  const int n0 = nt * 64, t0 = tt * 96;

  const int e0 = pair_e[b * 2], e1 = pair_e[b * 2 + 1];
  const float g0 = pair_gate[b * 2], g1 = pair_gate[b * 2 + 1];
  const bf16* Agb0 = h + ((size_t)(b * 2) * 6 + nt) * 131072;
  const bf16* Agb1 = h + ((size_t)(b * 2 + 1) * 6 + nt) * 131072;
  const bf16* Bgb0 = W2B + ((size_t)(layer * E_ + e0) * 4 + tt) * 196608;
  const bf16* Bgb1 = W2B + ((size_t)(layer * E_ + e1) * 4 + tt) * 196608;
  const int quad = lane >> 4, l15 = lane & 15;
  const int wm = w >> 1, wt = w & 1;   // wave tile: 32(n) x 48(t)

  if (tid < 96) {
    int t = t0 + tid;
    bias_t[tid] = (t < T_)
        ? g0 * be2[(layer * E_ + e0) * T_ + t] + g1 * be2[(layer * E_ + e1) * T_ + t]
        : 0.f;
  }
  // drain all prior VMEM (divergent bias loads) so per-thread vmcnt is exactly
  // the 5 staging loads per K-step from here on.
  pipe_barrier_full();

  f32x4 acc[2][3];
  const f32x4 zero = {0.f, 0.f, 0.f, 0.f};
  #pragma unroll
  for (int i = 0; i < 2; i++)
    #pragma unroll
    for (int jj = 0; jj < 3; jj++) acc[i][jj] = zero;

  const int aoff = w * 1024 + lane * 8;   // per-thread staging offsets (els)
  const int boff = w * 1536 + lane * 8;

  auto stageA = [&](const bf16* Aj, int buf) {   // 2 loads/thread
    bf16* As2 = S + buf * 4096;
    async_copy16(Aj + aoff, As2 + w * 1024);
    async_copy16(Aj + aoff + 512, As2 + w * 1024 + 512);
  };
  auto stageB = [&](const bf16* Bj, int buf) {   // 3 loads/thread
    bf16* Bs2 = S + 12288 + buf * 6144;
    async_copy16(Bj + boff, Bs2 + w * 1536);
    async_copy16(Bj + boff + 512, Bs2 + w * 1536 + 512);
    async_copy16(Bj + boff + 1024, Bs2 + w * 1536 + 1024);
  };

  auto compute = [&](int bufA, int bufB) {
    const bf16* As2 = S + bufA * 4096;
    const bf16* Bs2 = S + 12288 + bufB * 6144;
    #pragma unroll
    for (int w32 = 0; w32 < 2; w32++) {
      const int kg = w32 * 4 + quad;
      bf16x8 af[2], bfr[3];
      #pragma unroll
      for (int mi = 0; mi < 2; mi++)
        af[mi] = *(const bf16x8*)(As2 + kg * 512 + (wm * 32 + mi * 16 + l15) * 8);
      #pragma unroll
      for (int ni = 0; ni < 3; ni++)
        bfr[ni] = *(const bf16x8*)(Bs2 + kg * 768 + (wt * 48 + ni * 16 + l15) * 8);
      #pragma unroll
      for (int mi = 0; mi < 2; mi++)
        #pragma unroll
        for (int ni = 0; ni < 3; ni++)
          acc[mi][ni] = __builtin_amdgcn_mfma_f32_16x16x32_bf16(af[mi], bfr[ni], acc[mi][ni], 0, 0, 0);
    }
  };

  // prologue: B(0)->b0, A(0)->a0, A(1)->a1; wait all but the newest 2 (A(1)).
  stageB(Bgb0, 0);
  stageA(Agb0, 0);
  stageA(Agb0 + 4096, 1);
  G2_WAITN(2);

  const bf16* aNext = Agb0 + 2 * 4096;  // A(2)
  const bf16* bNext = Bgb0 + 6144;      // B(1)

  // main loop: k = 0..59, 6 steps per iteration (lcm of 3 A-bufs, 2 B-bufs).
  // Step k: issue B(k+1), issue A(k+2) (newest), compute(k), wait vmcnt(2).
  #pragma unroll 1
  for (int j = 0; j < 10; ++j) {
    const int k = j * 6;
#define G2S(i, bB1, bA2, cA, cB)                              \
    stageB(bNext, bB1);                                       \
    stageA(aNext, bA2);                                       \
    bNext = (k + (i) == 30) ? Bgb1 : bNext + 6144;            \
    aNext = (k + (i) == 29) ? Agb1 : aNext + 4096;            \
    compute(cA, cB);                                          \
    G2_WAITN(2);
    G2S(0, 1, 2, 0, 0)
    G2S(1, 0, 0, 1, 1)
    G2S(2, 1, 1, 2, 0)
    G2S(3, 0, 2, 0, 1)
    G2S(4, 1, 0, 1, 0)
    G2S(5, 0, 1, 2, 1)
#undef G2S
  }

  // tail: k = 60..63
  stageB(bNext, 1);          // B(61)
  stageA(aNext, 2);          // A(62)
  bNext += 6144; aNext += 4096;
  compute(0, 0);             // k=60
  G2_WAITN(2);

  stageB(bNext, 0);          // B(62)
  stageA(aNext, 0);          // A(63)
  bNext += 6144;
  compute(1, 1);             // k=61
  G2_WAITN(2);

  stageB(bNext, 1);          // B(63)
  compute(2, 0);             // k=62
  G2_WAITN(0);

  compute(0, 1);             // k=63
  pipe_barrier_full();       // all ds_reads done before S reuse below

  // ---- fused pack epilogue: residual merge -> out (fp32) + C-tile -> LDS (bf16)
  #pragma unroll
  for (int mi = 0; mi < 2; mi++) {
    #pragma unroll
    for (int ni = 0; ni < 3; ni++) {
      int nloc_b = wm * 32 + mi * 16 + quad * 4;
      int tloc = wt * 48 + ni * 16 + l15;
      int t = t0 + tloc;
      #pragma unroll
      for (int r = 0; r < 4; r++) {
        int nloc = nloc_b + r;
        int n = n0 + nloc;
        float vv = 0.f;
        if (n < N_ && t < T_) {
          size_t q = ((size_t)b * T_ + t) * N_ + n;
          vv = out[q] + acc[mi][ni][r] + bias_t[tloc];
          out[q] = vv;
        }
        S[nloc * CT_STRIDE + tloc] = __float2bfloat16(vv);
      }
    }
  }
  __syncthreads();
  // transpose-store Abuf rows (coalesced 16B segments); pad cols (t>=T) get zeros
  #pragma unroll
  for (int it = 0; it < 3; ++it) {
    int idx = tid + it * 256;          // < 768 = 64 rows * 12 segs
    int row = idx / 12, seg = idx % 12;
    int t = t0 + seg * 8;
    if (t < TPAD)
      *(uint4*)(Abuf + ((size_t)b * NPAD + n0 + row) * TPAD + t) =
          *(const uint4*)(S + row * CT_STRIDE + seg * 8);
  }
}

// ---------------- projection head: fused two-stage MFMA -----------------------------
// 64 rows/block, grid (6,B) = 192 blocks; one 16-row MFMA strip per wave.
#define HS_STRIDE 104  // 96 + 8 pad (208B row stride, 16B-aligned)
__global__ __launch_bounds__(256) void proj_kernel(
    const bf16* __restrict__ Abuf, const bf16* __restrict__ P1T, const float* __restrict__ P1b,
    const bf16* __restrict__ P2T, const float* __restrict__ P2b,
    const float* __restrict__ loss_partial, float* __restrict__ dout) {
  __shared__ __align__(16) bf16 Hs[64 * HS_STRIDE];
  const int tid = threadIdx.x;
  const int w = tid >> 6, lane = tid & 63;
  const int quad = lane >> 4, l15 = lane & 15;
  const int b = blockIdx.y;
  const int m0 = blockIdx.x * 64;
  const int row = w * 16;              // wave's row strip within the 64-row tile

  f32x4 acc1[6];
  const f32x4 zero = {0.f, 0.f, 0.f, 0.f};
  #pragma unroll
  for (int j = 0; j < 6; j++) acc1[j] = zero;

  const bf16* Arow = Abuf + ((size_t)b * NPAD + m0 + row) * TPAD;
  for (int kk = 0; kk < TPAD / 32; ++kk) {
    bf16x8 af, bfr[6];
    af = *(const bf16x8*)(Arow + (size_t)l15 * TPAD + kk * 32 + quad * 8);
    #pragma unroll
    for (int ni = 0; ni < 6; ni++)
      bfr[ni] = *(const bf16x8*)(P1T + (size_t)(ni * 16 + l15) * TPAD + kk * 32 + quad * 8);
    #pragma unroll
    for (int ni = 0; ni < 6; ni++)
      acc1[ni] = __builtin_amdgcn_mfma_f32_16x16x32_bf16(af, bfr[ni], acc1[ni], 0, 0, 0);
  }

  #pragma unroll
  for (int ni = 0; ni < 6; ni++) {
    float bias = P1b[ni * 16 + l15];
    #pragma unroll
    for (int r = 0; r < 4; r++) {
      float x = acc1[ni][r] + bias;
      float t = 1.f - 2.f / (__expf(2.f * x) + 1.f);
      Hs[(row + quad * 4 + r) * HS_STRIDE + ni * 16 + l15] = __float2bfloat16(t);
    }
  }
  __syncthreads();

  #pragma unroll
  for (int half = 0; half < 2; ++half) {
    f32x4 acc2[6];
    #pragma unroll
    for (int j = 0; j < 6; j++) acc2[j] = zero;

    #pragma unroll
    for (int kk = 0; kk < 3; ++kk) {
      bf16x8 af, bfr[6];
      af = *(const bf16x8*)(Hs + (row + l15) * HS_STRIDE + kk * 32 + quad * 8);
      #pragma unroll
      for (int ni = 0; ni < 6; ni++)
        bfr[ni] = *(const bf16x8*)(P2T + (size_t)((half * 6 + ni) * 16 + l15) * P_ + kk * 32 + quad * 8);
      #pragma unroll
      for (int ni = 0; ni < 6; ni++)
        acc2[ni] = __builtin_amdgcn_mfma_f32_16x16x32_bf16(af, bfr[ni], acc2[ni], 0, 0, 0);
    }

    #pragma unroll
    for (int ni = 0; ni < 6; ni++) {
      int jj = (half * 6 + ni) * 16 + l15;
      float bias = P2b[jj];
      int pout = jj >> 1;
      #pragma unroll
      for (int r = 0; r < 4; r++) {
        int n = m0 + row + quad * 4 + r;
        if (n < N_) {
          float s = acc2[ni][r] + bias;
          size_t o = ((size_t)b * P_ + pout) * N_ + n;
          if ((jj & 1) == 0) {
            dout[o] = s;
          } else {
            float sp = (s > 20.f) ? s : log1pf(__expf(s));
            dout[(size_t)B_ * P_ * N_ + 1 + o] = sp + 1e-6f;
          }
        }
      }
    }
  }
  if (b == 0 && blockIdx.x == 0 && tid == 0)
    dout[(size_t)B_ * P_ * N_] = loss_partial[0] + loss_partial[1];
}

// ----------------------------------------------------------------------------------
extern "C" void kernel_launch(void* const* d_in, const int* in_sizes, int n_in,
                              void* d_out, int out_size, void* d_ws, size_t ws_size,
                              hipStream_t stream) {
  const float* x   = (const float*)d_in[0];
  const float* Wg  = (const float*)d_in[11];
  const float* We1 = (const float*)d_in[12];
  const float* be1 = (const float*)d_in[13];
  const float* We2 = (const float*)d_in[14];
  const float* be2 = (const float*)d_in[15];
  const float* P1w = (const float*)d_in[16];
  const float* P1b = (const float*)d_in[17];
  const float* P2w = (const float*)d_in[18];
  const float* P2b = (const float*)d_in[19];

  char* ws = (char*)d_ws;
  size_t off = 0;
  auto alloc = [&](size_t bytes) -> void* {
    void* p = ws + off;
    off += (bytes + 255) & ~(size_t)255;
    return p;
  };
  float* out        = (float*)alloc((size_t)B_ * T_ * N_ * 4);
  bf16*  Abuf       = (bf16*) alloc((size_t)B_ * NPAD * TPAD * 2);
  bf16*  W1T        = (bf16*) alloc((size_t)L_ * E_ * F_ * TPAD * 2);
  bf16*  W2B        = (bf16*) alloc((size_t)L_ * E_ * 4 * 196608 * 2);
  bf16*  P1T        = (bf16*) alloc((size_t)P_ * TPAD * 2);
  bf16*  P2T        = (bf16*) alloc((size_t)2 * P_ * P_ * 2);
  bf16*  h          = (bf16*) alloc((size_t)B_ * 2 * 786432 * 2);
  float* colsum     = (float*)alloc((size_t)B_ * T_ * 4);
  int*   pair_e     = (int*)  alloc(B_ * 2 * 4);
  float* pair_gate  = (float*)alloc(B_ * 2 * 4);
  float* loss_part  = (float*)alloc(2 * 4);
  if (ws_size < off) return;  // workspace too small — bail instead of corrupting

  dim3 tb(32, 8);
  transpose_cast_kernel<<<dim3(11, 64, 8), tb, 0, stream>>>(
      We1, W1T, T_, F_, TPAD, F_, (long long)T_ * F_, (long long)F_ * TPAD);
  repack_w2_kernel<<<dim3(64, 4, 8), 256, 0, stream>>>(We2, W2B);
  transpose_cast_kernel<<<dim3(11, 3, 1), tb, 0, stream>>>(
      P1w, P1T, T_, P_, TPAD, P_, 0, 0);
  transpose_cast_kernel<<<dim3(3, 6, 1), tb, 0, stream>>>(
      P2w, P2T, P_, 2 * P_, P_, 2 * P_, 0, 0);

  revin_kernel<<<dim3(B_, 6), 512, 0, stream>>>(x, out, Abuf);

  for (int l = 0; l < L_; ++l) {
    gate1_kernel<<<dim3(21, B_), 256, 0, stream>>>(out, colsum);
    gate2_kernel<<<1, 128, 0, stream>>>(colsum, Wg, pair_e, pair_gate, loss_part, l);
    gemm1_kernel<<<dim3(16, 3, 64), 256, 0, stream>>>(Abuf, W1T, be1, pair_e, pair_gate, h, l);
    gemm2_kernel<<<768, 256, 0, stream>>>(h, W2B, be2, pair_e, pair_gate, out, Abuf, l);
  }

  proj_kernel<<<dim3(6, B_), 256, 0, stream>>>(Abuf, P1T, P1b, P2T, P2b, loss_part,
                                               (float*)d_out);
}

// Round 9
// 496.432 us; speedup vs baseline: 1.3975x; 1.0160x over previous
//
#include <hip/hip_runtime.h>
#include <hip/hip_bf16.h>
#include <cstdint>
#include <math.h>

#define B_ 32
#define T_ 336
#define N_ 321
#define L_ 2
#define E_ 4
#define F_ 2048
#define P_ 96
#define TPAD 352   // T padded to multiple of 32 (K of GEMM1 / proj stage1)
#define NPAD 384   // N padded to multiple of 128 (M tiles)

typedef __hip_bfloat16 bf16;
typedef __attribute__((ext_vector_type(8))) __bf16 bf16x8;
typedef __attribute__((ext_vector_type(4))) float f32x4;

// h blocked layout: h[pair][nb][kg][row64][8]  (kg = f/8, j = f%8)
//   kg stride 512 els, nb stride 131072 els, pair stride 786432 els.
// W2 blocked layout: W2B[le][tb][kg][row96][8]
//   kg stride 768 els, tb stride 196608 els, le stride 786432 els.
// Gating is FUSED: colsum[b,t] (sum over n of the running residual) is produced
// by revin (layer 0) and gemm2's epilogue (layer 1) via atomics into a
// double-buffered colsum[2][B][T]; each GEMM block recomputes the top-2 gate
// inline (identical shared routine -> identical selection); the cv^2 balance
// loss is computed by wave 1 of gemm1 block 0. gate1/gate2 kernels are gone.
// gemm2 keeps R8's asymmetric-depth pipeline: A (h, HBM) 3-buffered 2-ahead,
// B (W2B, L2) 2-buffered 1-ahead, counted vmcnt(2) at the per-step barrier.

__device__ __forceinline__ void async_copy16(const void* g, void* l) {
  __builtin_amdgcn_global_load_lds(
      (__attribute__((address_space(1))) void*)(uintptr_t)g,
      (__attribute__((address_space(3))) void*)(unsigned int)(uintptr_t)l,
      16, 0, 0);
}

__device__ __forceinline__ void pipe_barrier_vm0() {
  asm volatile("s_waitcnt vmcnt(0)" ::: "memory");
  __builtin_amdgcn_s_barrier();
  __builtin_amdgcn_sched_barrier(0);
}

__device__ __forceinline__ void pipe_barrier_full() {
  asm volatile("s_waitcnt vmcnt(0) lgkmcnt(0)" ::: "memory");
  __builtin_amdgcn_s_barrier();
  __builtin_amdgcn_sched_barrier(0);
}

#define G2_WAITN(N)                                         \
  do {                                                      \
    asm volatile("s_waitcnt vmcnt(" #N ")" ::: "memory");   \
    __builtin_amdgcn_s_barrier();                           \
    __builtin_amdgcn_sched_barrier(0);                      \
  } while (0)

// ---------------- shared gating routines (identical everywhere) --------------------
// wave0 (tid<64) computes the 4 logits into lgs[0..3]; caller syncs then all
// threads derive top-2 from lgs with the same arithmetic.
__device__ __forceinline__ void gate_logits(const float* __restrict__ cs,
                                            const float* __restrict__ Wg,
                                            int layer, int b, float* lgs, int tid) {
  if (tid < 64) {
    const int e = tid & 3, toff = tid >> 2;   // 16 t-offsets x 4 experts
    float s = 0.f;
    for (int j = 0; j < 21; j++) {            // 16*21 = 336 = T_
      int t = toff + (j << 4);
      s += cs[b * T_ + t] * Wg[(layer * T_ + t) * E_ + e];
    }
    #pragma unroll
    for (int m = 4; m < 64; m <<= 1) s += __shfl_xor(s, m);
    if (tid < 4) lgs[tid] = s / (float)N_;
  }
}

__device__ __forceinline__ void top2_from(const float* lgs, int& i0, int& i1,
                                          float& g0, float& g1) {
  float v[4] = {lgs[0], lgs[1], lgs[2], lgs[3]};
  i0 = 0;
  for (int e = 1; e < 4; e++) if (v[e] > v[i0]) i0 = e;   // lowest index wins ties
  i1 = -1;
  for (int e = 0; e < 4; e++) {
    if (e == i0) continue;
    if (i1 < 0 || v[e] > v[i1]) i1 = e;
  }
  float ex = expf(v[i1] - v[i0]);
  g0 = 1.f / (1.f + ex);
  g1 = ex / (1.f + ex);
}

// one wave computes the cv^2 balance loss for a layer (lane = b for lane<32)
__device__ __forceinline__ void balance_loss(const float* __restrict__ cs,
                                             const float* __restrict__ Wg,
                                             int layer, int lane,
                                             float* __restrict__ loss_partial) {
  float gg0 = 0.f, gg1 = 0.f, gg2 = 0.f, gg3 = 0.f;
  if (lane < 32) {
    const int bb = lane;
    float s0 = 0.f, s1 = 0.f, s2 = 0.f, s3 = 0.f;
    for (int t = 0; t < T_; t++) {
      float c = cs[bb * T_ + t];
      const float* wr = Wg + (size_t)(layer * T_ + t) * E_;
      s0 += c * wr[0]; s1 += c * wr[1]; s2 += c * wr[2]; s3 += c * wr[3];
    }
    float v[4] = {s0 / (float)N_, s1 / (float)N_, s2 / (float)N_, s3 / (float)N_};
    int i0 = 0;
    for (int e = 1; e < 4; e++) if (v[e] > v[i0]) i0 = e;
    int i1 = -1;
    for (int e = 0; e < 4; e++) {
      if (e == i0) continue;
      if (i1 < 0 || v[e] > v[i1]) i1 = e;
    }
    float ex = expf(v[i1] - v[i0]);
    float a = 1.f / (1.f + ex), q = ex / (1.f + ex);
    gg0 = (i0 == 0) ? a : ((i1 == 0) ? q : 0.f);
    gg1 = (i0 == 1) ? a : ((i1 == 1) ? q : 0.f);
    gg2 = (i0 == 2) ? a : ((i1 == 2) ? q : 0.f);
    gg3 = (i0 == 3) ? a : ((i1 == 3) ? q : 0.f);
  }
  #pragma unroll
  for (int m = 1; m < 32; m <<= 1) {
    gg0 += __shfl_xor(gg0, m); gg1 += __shfl_xor(gg1, m);
    gg2 += __shfl_xor(gg2, m); gg3 += __shfl_xor(gg3, m);
  }
  if (lane == 0) {
    float mm = (gg0 + gg1 + gg2 + gg3) * 0.25f;
    float d0 = gg0 - mm, d1 = gg1 - mm, d2 = gg2 - mm, d3 = gg3 - mm;
    float va = (d0 * d0 + d1 * d1 + d2 * d2 + d3 * d3) * 0.25f;
    loss_partial[layer] = 0.01f * (va / (mm * mm + 1e-10f));
  }
}

// ---------------- transpose + cast fp32 -> bf16 (K-contiguous operand prep) ----------
__global__ void transpose_cast_kernel(const float* __restrict__ src, bf16* __restrict__ dst,
                                      int R, int C, int Rp, int Cp,
                                      long long sStride, long long dStride) {
  __shared__ float tile[32][33];
  const float* s = src + (size_t)blockIdx.z * sStride;
  bf16* d = dst + (size_t)blockIdx.z * dStride;
  int r0 = blockIdx.x * 32, c0 = blockIdx.y * 32;
  int tx = threadIdx.x, ty = threadIdx.y;
  #pragma unroll
  for (int ii = 0; ii < 4; ii++) {
    int rl = ty * 4 + ii;
    int r = r0 + rl, c = c0 + tx;
    tile[rl][tx] = (r < R && c < C) ? s[(size_t)r * C + c] : 0.f;
  }
  __syncthreads();
  #pragma unroll
  for (int ii = 0; ii < 4; ii++) {
    int cl = ty * 4 + ii;
    int cd = c0 + cl, rd = r0 + tx;
    if (cd < Cp && rd < Rp)
      d[(size_t)cd * Rp + rd] = __float2bfloat16(tile[tx][cl]);
  }
}

// ---------------- We2 -> k-blocked W2B ---------------------------------------------
// grid (F/32, 4, L*E); dst[le][tb][kg][row96][8] = We2[le][f=kg*8+j][t=tb*96+row]
__global__ void repack_w2_kernel(const float* __restrict__ src, bf16* __restrict__ dst) {
  __shared__ float tile[32][96];
  int le = blockIdx.z, tb = blockIdx.y, f0 = blockIdx.x * 32;
  int tid = threadIdx.x;
  const float* s = src + (size_t)le * F_ * T_;
  for (int idx = tid; idx < 32 * 96; idx += 256) {
    int ff = idx / 96, tt = idx % 96;
    int t = tb * 96 + tt;
    tile[ff][tt] = (t < T_) ? s[(size_t)(f0 + ff) * T_ + t] : 0.f;
  }
  __syncthreads();
  bf16* d = dst + ((size_t)le * 4 + tb) * 196608 + (size_t)(f0 >> 3) * 768;
  for (int s2 = tid; s2 < 384; s2 += 256) {
    int kgl = s2 / 96, row = s2 % 96;
    bf16 v[8];
    #pragma unroll
    for (int j = 0; j < 8; j++) v[j] = __float2bfloat16(tile[kgl * 8 + j][row]);
    *(uint4*)(d + (size_t)kgl * 768 + row * 8) = *(const uint4*)v;
  }
}

// ---------------- RevIN + initial pack: x -> out (fp32), Abuf (bf16), colsum --------
// 512 threads: 64 n-lanes x 8 t-quarters (42 t each). Also produces
// colsum0[b,t] = sum_n out[b,t,n] via wave butterfly + atomicAdd (layer-0 gating).
__global__ __launch_bounds__(512) void revin_kernel(const float* __restrict__ x,
                                                    float* __restrict__ out,
                                                    bf16* __restrict__ Abuf,
                                                    float* __restrict__ cs0) {
  __shared__ float red[8][64][2];
  __shared__ float minv[64][2];
  __shared__ unsigned int Lt[64][177];   // 176 used cols (= TPAD/2 uints per row)

  const int b = blockIdx.x;
  const int n0 = blockIdx.y * 64;
  const int tid = threadIdx.x;
  const int nl = tid & 63, tq = tid >> 6;      // tq 0..7
  const int n = n0 + nl;
  const bool valid = (n < N_);
  const float* xp = x + ((size_t)b * T_ * N_ + n) * 3;
  const int tbeg = tq * 42, tend = tbeg + 42;  // 8*42 = 336 = T_

  // pass 1: partial sums over this thread's t-range
  float s1 = 0.f, s2 = 0.f;
  if (valid) {
    for (int t = tbeg; t < tend; t++) {
      float v = xp[(size_t)t * N_ * 3];
      s1 += v; s2 += v * v;
    }
  }
  red[tq][nl][0] = s1; red[tq][nl][1] = s2;
  __syncthreads();
  if (tid < 64) {
    float a = 0.f, c = 0.f;
    #pragma unroll
    for (int q = 0; q < 8; q++) { a += red[q][tid][0]; c += red[q][tid][1]; }
    float mu = a / (float)T_;
    float var = c / (float)T_ - mu * mu;
    minv[tid][0] = mu;
    minv[tid][1] = 1.f / sqrtf(var + 1e-5f);
  }
  // zero the pad cols (t in [336,352) -> uint cols 168..175): 64 rows x 8 cols
  {
    int r = tid >> 3, c = 168 + (tid & 7);
    Lt[r][c] = 0u;
  }
  __syncthreads();

  const float mu = minv[nl][0], inv = minv[nl][1];
  // pass 2: normalize, write out (coalesced), stage packed bf16 pairs into LDS,
  // and accumulate colsum over this block's 64 n's (wave butterfly, lane0 atomic).
  for (int t = tbeg; t < tend; t += 2) {
    float v0 = 0.f, v1 = 0.f;
    if (valid) {
      v0 = (xp[(size_t)t * N_ * 3] - mu) * inv;
      v1 = (xp[(size_t)(t + 1) * N_ * 3] - mu) * inv;
      out[((size_t)b * T_ + t) * N_ + n] = v0;
      out[((size_t)b * T_ + t + 1) * N_ + n] = v1;
    }
    float c0 = v0, c1 = v1;
    #pragma unroll
    for (int m = 1; m < 64; m <<= 1) {
      c0 += __shfl_xor(c0, m);
      c1 += __shfl_xor(c1, m);
    }
    if (nl == 0) {
      atomicAdd(cs0 + b * T_ + t, c0);
      atomicAdd(cs0 + b * T_ + t + 1, c1);
    }
    bf16 h0 = __float2bfloat16(v0), h1 = __float2bfloat16(v1);
    unsigned int u = (unsigned int)*(unsigned short*)&h0 |
                     ((unsigned int)*(unsigned short*)&h1 << 16);
    Lt[nl][t >> 1] = u;
  }
  __syncthreads();

  // copy-out: 64 rows x 176 uints = 11264 uints, 22 per thread, coalesced
  unsigned int* abase = (unsigned int*)(Abuf + ((size_t)b * NPAD + n0) * TPAD);
  #pragma unroll
  for (int k = 0; k < 22; k++) {
    int idx = tid + k * 512;
    int row = idx / 176, c = idx % 176;
    abase[(size_t)row * (TPAD / 2) + c] = Lt[row][c];
  }
}

// ---------------- GEMM1: h[pair] = gate * relu(Abuf[b] @ We1[l,e] + be1) ------------
// h written in blocked layout (see top). 2-phase pipelined. Gating inline (wave0);
// balance loss by wave1 of block (0,0,0).
__global__ __launch_bounds__(256) void gemm1_kernel(
    const bf16* __restrict__ Abuf, const bf16* __restrict__ W1T,
    const float* __restrict__ be1, const float* __restrict__ cs,
    const float* __restrict__ Wg, float* __restrict__ loss_partial,
    bf16* __restrict__ h, int layer) {
  // buf b: A = S1 + b*8192 (128x32), B = S1 + b*8192 + 4096 (128x32)
  __shared__ __align__(16) bf16 S1[16384];
  __shared__ float bias_s[128];
  __shared__ float lgs[4];

  const int tid = threadIdx.x;
  const int w = tid >> 6, lane = tid & 63;
  const int pair = blockIdx.z;
  const int b = pair >> 1;
  const int m0 = blockIdx.y * 128;  // n-dim
  const int f0 = blockIdx.x * 128;

  gate_logits(cs, Wg, layer, b, lgs, tid);
  if (blockIdx.x == 0 && blockIdx.y == 0 && pair == 0 && w == 1)
    balance_loss(cs, Wg, layer, lane, loss_partial);
  __syncthreads();
  int i0, i1; float ga, gb;
  top2_from(lgs, i0, i1, ga, gb);
  const int e = __builtin_amdgcn_readfirstlane((pair & 1) ? i1 : i0);
  const float gate = (pair & 1) ? gb : ga;

  const bf16* Ag = Abuf + (size_t)b * NPAD * TPAD + (size_t)m0 * TPAD;
  const bf16* Bg = W1T + ((size_t)(layer * E_ + e) * F_ + f0) * TPAD;
  if (tid < 128) bias_s[tid] = be1[(size_t)(layer * E_ + e) * F_ + f0 + tid];

  f32x4 acc[4][4];
  const f32x4 zero = {0.f, 0.f, 0.f, 0.f};
  #pragma unroll
  for (int i = 0; i < 4; i++)
    #pragma unroll
    for (int j = 0; j < 4; j++) acc[i][j] = zero;

  const int wm = w >> 1, wn = w & 1;
  const int lrow = lane >> 2;          // 64B-coalesced staging
  const int lkoff = (lane & 3) * 8;
  const int quad = lane >> 4;
  const int l15 = lane & 15;

  auto stage1 = [&](int k, int buf) {
    const int k0 = k * 32;
    bf16* As = S1 + buf * 8192;
    bf16* Bs = As + 4096;
    #pragma unroll
    for (int i = 0; i < 2; i++) {
      int r = (w * 2 + i) * 16 + lrow;
      async_copy16(Ag + (size_t)r * TPAD + k0 + lkoff, As + (w * 2 + i) * 512);
      async_copy16(Bg + (size_t)r * TPAD + k0 + lkoff, Bs + (w * 2 + i) * 512);
    }
  };

  stage1(0, 0);
  pipe_barrier_full();

  for (int kk = 0; kk < TPAD / 32; ++kk) {
    if (kk < TPAD / 32 - 1) stage1(kk + 1, (kk + 1) & 1);
    const bf16* As = S1 + (kk & 1) * 8192;
    const bf16* Bs = As + 4096;
    bf16x8 af[4], bfr[4];
    #pragma unroll
    for (int mi = 0; mi < 4; mi++)
      af[mi] = *(const bf16x8*)(As + (wm * 64 + mi * 16 + l15) * 32 + quad * 8);
    #pragma unroll
    for (int ni = 0; ni < 4; ni++)
      bfr[ni] = *(const bf16x8*)(Bs + (wn * 64 + ni * 16 + l15) * 32 + quad * 8);
    #pragma unroll
    for (int mi = 0; mi < 4; mi++)
      #pragma unroll
      for (int ni = 0; ni < 4; ni++)
        acc[mi][ni] = __builtin_amdgcn_mfma_f32_16x16x32_bf16(af[mi], bfr[ni], acc[mi][ni], 0, 0, 0);
    pipe_barrier_vm0();
  }

  // epilogue: bias + relu + gate, LDS transpose, then blocked-layout h stores
  bf16* tw0 = S1 + w * 1024;          // per-wave private scratch (buf0 A region)
  bf16* tw1 = S1 + 4096 + w * 1024;   // per-wave private scratch (buf0 B region)
  // this wave's rows live in nb = m0/64 + wm, rows mi*16 + (lane>>2)
  size_t hb = (size_t)pair * 786432 + (size_t)((m0 >> 6) + wm) * 131072;
  const int kgbase = (f0 >> 3) + wn * 8 + (lane & 3) * 2;
  #pragma unroll
  for (int mi = 0; mi < 4; mi++) {
    bf16* tw = (mi & 1) ? tw1 : tw0;
    #pragma unroll
    for (int ni = 0; ni < 4; ni++) {
      float bias = bias_s[wn * 64 + ni * 16 + l15];
      #pragma unroll
      for (int r = 0; r < 4; r++) {
        float v = acc[mi][ni][r] + bias;
        v = fmaxf(v, 0.f) * gate;
        tw[(quad * 4 + r) * 64 + ni * 16 + l15] = __float2bfloat16(v);
      }
    }
    int row = lane >> 2;            // 0..15
    int fpart = (lane & 3) * 16;    // 0,16,32,48
    const uint4* sp = (const uint4*)(tw + row * 64 + fpart);
    uint4 d0 = sp[0];
    uint4 d1 = sp[1];
    bf16* dp = h + hb + (size_t)kgbase * 512 + (mi * 16 + row) * 8;
    *(uint4*)dp = d0;
    *(uint4*)(dp + 512) = d1;
  }
}

// ---------------- GEMM2+pack fused: both experts per block, K=4096 ------------------
// out[b,t,n] += h@We2 (both experts) + gated be2; Abuf[b,n,t] = bf16(out).
// Gating inline (wave0). Epilogue also accumulates colsum for the NEXT layer's
// gating (LDS reduce + one global atomic per t; layer 0 only).
// Pipeline: A 3-buffered 2-ahead, B 2-buffered 1-ahead, counted vmcnt(2).
// XCD swizzle keeps the 4 t-tiles of a (b,n)-group on one XCD.
#define CT_STRIDE 104
__global__ __launch_bounds__(256) void gemm2_kernel(
    const bf16* __restrict__ h, const bf16* __restrict__ W2B,
    const float* __restrict__ be2, const float* __restrict__ cs_cur,
    float* __restrict__ cs_next, const float* __restrict__ Wg,
    float* __restrict__ out, bf16* __restrict__ Abuf, int layer) {
  // S layout (els): A0@0 A1@4096 A2@8192 | B0@12288 B1@18432 | end 24576 (48KB).
  // epilogue reuses first 64*CT_STRIDE = 6656 els as bf16 C-tile.
  __shared__ __align__(16) bf16 S[24576];
  __shared__ float bias_t[96];
  __shared__ float lgs[4];
  __shared__ float csl[96];

  const int tid = threadIdx.x;
  const int w = tid >> 6, lane = tid & 63;
  const int id = blockIdx.x;           // 0..767
  const int u = id & 7;                // XCD (round-robin heuristic)
  const int v = id >> 3;               // 0..95
  const int tt = v & 3;
  const int pn = u + 8 * (v >> 2);     // 0..191
  const int b = pn / 6, nt = pn % 6;
  const int n0 = nt * 64, t0 = tt * 96;

  gate_logits(cs_cur, Wg, layer, b, lgs, tid);
  if (tid < 96) csl[tid] = 0.f;
  __syncthreads();
  int i0, i1; float g0, g1;
  top2_from(lgs, i0, i1, g0, g1);
  const int e0 = __builtin_amdgcn_readfirstlane(i0);
  const int e1 = __builtin_amdgcn_readfirstlane(i1);

  const bf16* Agb0 = h + ((size_t)(b * 2) * 6 + nt) * 131072;
  const bf16* Agb1 = h + ((size_t)(b * 2 + 1) * 6 + nt) * 131072;
  const bf16* Bgb0 = W2B + ((size_t)(layer * E_ + e0) * 4 + tt) * 196608;
  const bf16* Bgb1 = W2B + ((size_t)(layer * E_ + e1) * 4 + tt) * 196608;
  const int quad = lane >> 4, l15 = lane & 15;
  const int wm = w >> 1, wt = w & 1;   // wave tile: 32(n) x 48(t)

  if (tid < 96) {
    int t = t0 + tid;
    bias_t[tid] = (t < T_)
        ? g0 * be2[(layer * E_ + e0) * T_ + t] + g1 * be2[(layer * E_ + e1) * T_ + t]
        : 0.f;
  }
  // drain all prior VMEM (gating + divergent bias loads) so per-thread vmcnt is
  // exactly the 5 staging loads per K-step from here on.
  pipe_barrier_full();

  f32x4 acc[2][3];
  const f32x4 zero = {0.f, 0.f, 0.f, 0.f};
  #pragma unroll
  for (int i = 0; i < 2; i++)
    #pragma unroll
    for (int jj = 0; jj < 3; jj++) acc[i][jj] = zero;

  const int aoff = w * 1024 + lane * 8;   // per-thread staging offsets (els)
  const int boff = w * 1536 + lane * 8;

  auto stageA = [&](const bf16* Aj, int buf) {   // 2 loads/thread
    bf16* As2 = S + buf * 4096;
    async_copy16(Aj + aoff, As2 + w * 1024);
    async_copy16(Aj + aoff + 512, As2 + w * 1024 + 512);
  };
  auto stageB = [&](const bf16* Bj, int buf) {   // 3 loads/thread
    bf16* Bs2 = S + 12288 + buf * 6144;
    async_copy16(Bj + boff, Bs2 + w * 1536);
    async_copy16(Bj + boff + 512, Bs2 + w * 1536 + 512);
    async_copy16(Bj + boff + 1024, Bs2 + w * 1536 + 1024);
  };

  auto compute = [&](int bufA, int bufB) {
    const bf16* As2 = S + bufA * 4096;
    const bf16* Bs2 = S + 12288 + bufB * 6144;
    #pragma unroll
    for (int w32 = 0; w32 < 2; w32++) {
      const int kg = w32 * 4 + quad;
      bf16x8 af[2], bfr[3];
      #pragma unroll
      for (int mi = 0; mi < 2; mi++)
        af[mi] = *(const bf16x8*)(As2 + kg * 512 + (wm * 32 + mi * 16 + l15) * 8);
      #pragma unroll
      for (int ni = 0; ni < 3; ni++)
        bfr[ni] = *(const bf16x8*)(Bs2 + kg * 768 + (wt * 48 + ni * 16 + l15) * 8);
      #pragma unroll
      for (int mi = 0; mi < 2; mi++)
        #pragma unroll
        for (int ni = 0; ni < 3; ni++)
          acc[mi][ni] = __builtin_amdgcn_mfma_f32_16x16x32_bf16(af[mi], bfr[ni], acc[mi][ni], 0, 0, 0);
    }
  };

  // prologue: B(0)->b0, A(0)->a0, A(1)->a1; wait all but the newest 2 (A(1)).
  stageB(Bgb0, 0);
  stageA(Agb0, 0);
  stageA(Agb0 + 4096, 1);
  G2_WAITN(2);

  const bf16* aNext = Agb0 + 2 * 4096;  // A(2)
  const bf16* bNext = Bgb0 + 6144;      // B(1)

  // main loop: k = 0..59, 6 steps per iteration (lcm of 3 A-bufs, 2 B-bufs).
  // Step k: issue B(k+1), issue A(k+2) (newest), compute(k), wait vmcnt(2).
  #pragma unroll 1
  for (int j = 0; j < 10; ++j) {
    const int k = j * 6;
#define G2S(i, bB1, bA2, cA, cB)                              \
    stageB(bNext, bB1);                                       \
    stageA(aNext, bA2);                                       \
    bNext = (k + (i) == 30) ? Bgb1 : bNext + 6144;            \
    aNext = (k + (i) == 29) ? Agb1 : aNext + 4096;            \
    compute(cA, cB);                                          \
    G2_WAITN(2);
    G2S(0, 1, 2, 0, 0)
    G2S(1, 0, 0, 1, 1)
    G2S(2, 1, 1, 2, 0)
    G2S(3, 0, 2, 0, 1)
    G2S(4, 1, 0, 1, 0)
    G2S(5, 0, 1, 2, 1)
#undef G2S
  }

  // tail: k = 60..63
  stageB(bNext, 1);          // B(61)
  stageA(aNext, 2);          // A(62)
  bNext += 6144; aNext += 4096;
  compute(0, 0);             // k=60
  G2_WAITN(2);

  stageB(bNext, 0);          // B(62)
  stageA(aNext, 0);          // A(63)
  bNext += 6144;
  compute(1, 1);             // k=61
  G2_WAITN(2);

  stageB(bNext, 1);          // B(63)
  compute(2, 0);             // k=62
  G2_WAITN(0);

  compute(0, 1);             // k=63
  pipe_barrier_full();       // all ds_reads done before S reuse below

  // ---- fused pack epilogue: residual merge -> out (fp32) + C-tile -> LDS (bf16)
  //      + per-t colsum partials for next layer's gating
  float ps[3] = {0.f, 0.f, 0.f};
  #pragma unroll
  for (int mi = 0; mi < 2; mi++) {
    #pragma unroll
    for (int ni = 0; ni < 3; ni++) {
      int nloc_b = wm * 32 + mi * 16 + quad * 4;
      int tloc = wt * 48 + ni * 16 + l15;
      int t = t0 + tloc;
      #pragma unroll
      for (int r = 0; r < 4; r++) {
        int nloc = nloc_b + r;
        int n = n0 + nloc;
        float vv = 0.f;
        if (n < N_ && t < T_) {
          size_t q = ((size_t)b * T_ + t) * N_ + n;
          vv = out[q] + acc[mi][ni][r] + bias_t[tloc];
          out[q] = vv;
        }
        ps[ni] += vv;   // vv==0 outside valid region
        S[nloc * CT_STRIDE + tloc] = __float2bfloat16(vv);
      }
    }
  }
  if (layer == 0) {
    #pragma unroll
    for (int ni = 0; ni < 3; ni++)
      atomicAdd(&csl[wt * 48 + ni * 16 + l15], ps[ni]);
  }
  __syncthreads();
  // transpose-store Abuf rows (coalesced 16B segments); pad cols (t>=T) get zeros
  #pragma unroll
  for (int it = 0; it < 3; ++it) {
    int idx = tid + it * 256;          // < 768 = 64 rows * 12 segs
    int row = idx / 12, seg = idx % 12;
    int t = t0 + seg * 8;
    if (t < TPAD)
      *(uint4*)(Abuf + ((size_t)b * NPAD + n0 + row) * TPAD + t) =
          *(const uint4*)(S + row * CT_STRIDE + seg * 8);
  }
  if (layer == 0 && tid < 96) {
    int t = t0 + tid;
    if (t < T_) atomicAdd(cs_next + b * T_ + t, csl[tid]);
  }
}

// ---------------- projection head: fused two-stage MFMA -----------------------------
// 64 rows/block, grid (6,B) = 192 blocks; one 16-row MFMA strip per wave.
#define HS_STRIDE 104  // 96 + 8 pad (208B row stride, 16B-aligned)
__global__ __launch_bounds__(256) void proj_kernel(
    const bf16* __restrict__ Abuf, const bf16* __restrict__ P1T, const float* __restrict__ P1b,
    const bf16* __restrict__ P2T, const float* __restrict__ P2b,
    const float* __restrict__ loss_partial, float* __restrict__ dout) {
  __shared__ __align__(16) bf16 Hs[64 * HS_STRIDE];
  const int tid = threadIdx.x;
  const int w = tid >> 6, lane = tid & 63;
  const int quad = lane >> 4, l15 = lane & 15;
  const int b = blockIdx.y;
  const int m0 = blockIdx.x * 64;
  const int row = w * 16;              // wave's row strip within the 64-row tile

  f32x4 acc1[6];
  const f32x4 zero = {0.f, 0.f, 0.f, 0.f};
  #pragma unroll
  for (int j = 0; j < 6; j++) acc1[j] = zero;

  const bf16* Arow = Abuf + ((size_t)b * NPAD + m0 + row) * TPAD;
  for (int kk = 0; kk < TPAD / 32; ++kk) {
    bf16x8 af, bfr[6];
    af = *(const bf16x8*)(Arow + (size_t)l15 * TPAD + kk * 32 + quad * 8);
    #pragma unroll
    for (int ni = 0; ni < 6; ni++)
      bfr[ni] = *(const bf16x8*)(P1T + (size_t)(ni * 16 + l15) * TPAD + kk * 32 + quad * 8);
    #pragma unroll
    for (int ni = 0; ni < 6; ni++)
      acc1[ni] = __builtin_amdgcn_mfma_f32_16x16x32_bf16(af, bfr[ni], acc1[ni], 0, 0, 0);
  }

  #pragma unroll
  for (int ni = 0; ni < 6; ni++) {
    float bias = P1b[ni * 16 + l15];
    #pragma unroll
    for (int r = 0; r < 4; r++) {
      float x = acc1[ni][r] + bias;
      float t = 1.f - 2.f / (__expf(2.f * x) + 1.f);
      Hs[(row + quad * 4 + r) * HS_STRIDE + ni * 16 + l15] = __float2bfloat16(t);
    }
  }
  __syncthreads();

  #pragma unroll
  for (int half = 0; half < 2; ++half) {
    f32x4 acc2[6];
    #pragma unroll
    for (int j = 0; j < 6; j++) acc2[j] = zero;

    #pragma unroll
    for (int kk = 0; kk < 3; ++kk) {
      bf16x8 af, bfr[6];
      af = *(const bf16x8*)(Hs + (row + l15) * HS_STRIDE + kk * 32 + quad * 8);
      #pragma unroll
      for (int ni = 0; ni < 6; ni++)
        bfr[ni] = *(const bf16x8*)(P2T + (size_t)((half * 6 + ni) * 16 + l15) * P_ + kk * 32 + quad * 8);
      #pragma unroll
      for (int ni = 0; ni < 6; ni++)
        acc2[ni] = __builtin_amdgcn_mfma_f32_16x16x32_bf16(af, bfr[ni], acc2[ni], 0, 0, 0);
    }

    #pragma unroll
    for (int ni = 0; ni < 6; ni++) {
      int jj = (half * 6 + ni) * 16 + l15;
      float bias = P2b[jj];
      int pout = jj >> 1;
      #pragma unroll
      for (int r = 0; r < 4; r++) {
        int n = m0 + row + quad * 4 + r;
        if (n < N_) {
          float s = acc2[ni][r] + bias;
          size_t o = ((size_t)b * P_ + pout) * N_ + n;
          if ((jj & 1) == 0) {
            dout[o] = s;
          } else {
            float sp = (s > 20.f) ? s : log1pf(__expf(s));
            dout[(size_t)B_ * P_ * N_ + 1 + o] = sp + 1e-6f;
          }
        }
      }
    }
  }
  if (b == 0 && blockIdx.x == 0 && tid == 0)
    dout[(size_t)B_ * P_ * N_] = loss_partial[0] + loss_partial[1];
}

// ----------------------------------------------------------------------------------
extern "C" void kernel_launch(void* const* d_in, const int* in_sizes, int n_in,
                              void* d_out, int out_size, void* d_ws, size_t ws_size,
                              hipStream_t stream) {
  const float* x   = (const float*)d_in[0];
  const float* Wg  = (const float*)d_in[11];
  const float* We1 = (const float*)d_in[12];
  const float* be1 = (const float*)d_in[13];
  const float* We2 = (const float*)d_in[14];
  const float* be2 = (const float*)d_in[15];
  const float* P1w = (const float*)d_in[16];
  const float* P1b = (const float*)d_in[17];
  const float* P2w = (const float*)d_in[18];
  const float* P2b = (const float*)d_in[19];

  char* ws = (char*)d_ws;
  size_t off = 0;
  auto alloc = [&](size_t bytes) -> void* {
    void* p = ws + off;
    off += (bytes + 255) & ~(size_t)255;
    return p;
  };
  float* out        = (float*)alloc((size_t)B_ * T_ * N_ * 4);
  bf16*  Abuf       = (bf16*) alloc((size_t)B_ * NPAD * TPAD * 2);
  bf16*  W1T        = (bf16*) alloc((size_t)L_ * E_ * F_ * TPAD * 2);
  bf16*  W2B        = (bf16*) alloc((size_t)L_ * E_ * 4 * 196608 * 2);
  bf16*  P1T        = (bf16*) alloc((size_t)P_ * TPAD * 2);
  bf16*  P2T        = (bf16*) alloc((size_t)2 * P_ * P_ * 2);
  bf16*  h          = (bf16*) alloc((size_t)B_ * 2 * 786432 * 2);
  float* colsum     = (float*)alloc((size_t)2 * B_ * T_ * 4);   // [layer][B][T]
  float* loss_part  = (float*)alloc(2 * 4);
  if (ws_size < off) return;  // workspace too small — bail instead of corrupting

  dim3 tb(32, 8);
  transpose_cast_kernel<<<dim3(11, 64, 8), tb, 0, stream>>>(
      We1, W1T, T_, F_, TPAD, F_, (long long)T_ * F_, (long long)F_ * TPAD);
  repack_w2_kernel<<<dim3(64, 4, 8), 256, 0, stream>>>(We2, W2B);
  transpose_cast_kernel<<<dim3(11, 3, 1), tb, 0, stream>>>(
      P1w, P1T, T_, P_, TPAD, P_, 0, 0);
  transpose_cast_kernel<<<dim3(3, 6, 1), tb, 0, stream>>>(
      P2w, P2T, P_, 2 * P_, P_, 2 * P_, 0, 0);

  hipMemsetAsync(colsum, 0, (size_t)2 * B_ * T_ * 4, stream);
  revin_kernel<<<dim3(B_, 6), 512, 0, stream>>>(x, out, Abuf, colsum);

  for (int l = 0; l < L_; ++l) {
    const float* cs = colsum + (size_t)l * B_ * T_;
    gemm1_kernel<<<dim3(16, 3, 64), 256, 0, stream>>>(
        Abuf, W1T, be1, cs, Wg, loss_part, h, l);
    gemm2_kernel<<<768, 256, 0, stream>>>(
        h, W2B, be2, cs, colsum + (size_t)B_ * T_, Wg, out, Abuf, l);
  }

  proj_kernel<<<dim3(6, B_), 256, 0, stream>>>(Abuf, P1T, P1b, P2T, P2b, loss_part,
                                               (float*)d_out);
}

// Round 10
// 488.179 us; speedup vs baseline: 1.4212x; 1.0169x over previous
//
#include <hip/hip_runtime.h>
#include <hip/hip_bf16.h>
#include <cstdint>
#include <math.h>

#define B_ 32
#define T_ 336
#define N_ 321
#define L_ 2
#define E_ 4
#define F_ 2048
#define P_ 96
#define TPAD 352   // T padded to multiple of 32 (K of GEMM1 / proj stage1)
#define NPAD 384   // N padded to multiple of 128 (M tiles)

typedef __hip_bfloat16 bf16;
typedef __attribute__((ext_vector_type(8))) __bf16 bf16x8;
typedef __attribute__((ext_vector_type(4))) float f32x4;

// h blocked layout: h[pair][nb][kg][row64][8]  (kg = f/8, j = f%8)
//   kg stride 512 els, nb stride 131072 els, pair stride 786432 els.
// W2 blocked layout: W2B[le][tb][kg][row96][8]
//   kg stride 768 els, tb stride 196608 els, le stride 786432 els.
// Gating is FUSED (no gate kernels): colsum via revin + gemm2 epilogue atomics,
// top-2 recomputed inline per block, loss by wave1 of gemm1 block 0.
// gemm1 R10: LDS bank-conflict fix via content swizzle (G21: linear gload_lds
// dest + permuted GLOBAL source + matching XOR on ds_read). Within each 64B
// row-chunk the k-part lands at slot kpart^((row>>1)&3) -> fragment reads hit
// 8 distinct bank-starts per 8-lane issue group (was 4-way conflict). Epilogue
// tw transpose similarly swizzled (colgroup ^ (quad<<1)).
// gemm2 keeps R8's asymmetric-depth pipeline: A (h, HBM) 3-buffered 2-ahead,
// B (W2B, L2) 2-buffered 1-ahead, counted vmcnt(2) at the per-step barrier.

__device__ __forceinline__ void async_copy16(const void* g, void* l) {
  __builtin_amdgcn_global_load_lds(
      (__attribute__((address_space(1))) void*)(uintptr_t)g,
      (__attribute__((address_space(3))) void*)(unsigned int)(uintptr_t)l,
      16, 0, 0);
}

__device__ __forceinline__ void pipe_barrier_vm0() {
  asm volatile("s_waitcnt vmcnt(0)" ::: "memory");
  __builtin_amdgcn_s_barrier();
  __builtin_amdgcn_sched_barrier(0);
}

__device__ __forceinline__ void pipe_barrier_full() {
  asm volatile("s_waitcnt vmcnt(0) lgkmcnt(0)" ::: "memory");
  __builtin_amdgcn_s_barrier();
  __builtin_amdgcn_sched_barrier(0);
}

#define G2_WAITN(N)                                         \
  do {                                                      \
    asm volatile("s_waitcnt vmcnt(" #N ")" ::: "memory");   \
    __builtin_amdgcn_s_barrier();                           \
    __builtin_amdgcn_sched_barrier(0);                      \
  } while (0)

// ---------------- shared gating routines (identical everywhere) --------------------
__device__ __forceinline__ void gate_logits(const float* __restrict__ cs,
                                            const float* __restrict__ Wg,
                                            int layer, int b, float* lgs, int tid) {
  if (tid < 64) {
    const int e = tid & 3, toff = tid >> 2;   // 16 t-offsets x 4 experts
    float s = 0.f;
    for (int j = 0; j < 21; j++) {            // 16*21 = 336 = T_
      int t = toff + (j << 4);
      s += cs[b * T_ + t] * Wg[(layer * T_ + t) * E_ + e];
    }
    #pragma unroll
    for (int m = 4; m < 64; m <<= 1) s += __shfl_xor(s, m);
    if (tid < 4) lgs[tid] = s / (float)N_;
  }
}

__device__ __forceinline__ void top2_from(const float* lgs, int& i0, int& i1,
                                          float& g0, float& g1) {
  float v[4] = {lgs[0], lgs[1], lgs[2], lgs[3]};
  i0 = 0;
  for (int e = 1; e < 4; e++) if (v[e] > v[i0]) i0 = e;   // lowest index wins ties
  i1 = -1;
  for (int e = 0; e < 4; e++) {
    if (e == i0) continue;
    if (i1 < 0 || v[e] > v[i1]) i1 = e;
  }
  float ex = expf(v[i1] - v[i0]);
  g0 = 1.f / (1.f + ex);
  g1 = ex / (1.f + ex);
}

// one wave computes the cv^2 balance loss for a layer (lane = b for lane<32)
__device__ __forceinline__ void balance_loss(const float* __restrict__ cs,
                                             const float* __restrict__ Wg,
                                             int layer, int lane,
                                             float* __restrict__ loss_partial) {
  float gg0 = 0.f, gg1 = 0.f, gg2 = 0.f, gg3 = 0.f;
  if (lane < 32) {
    const int bb = lane;
    float s0 = 0.f, s1 = 0.f, s2 = 0.f, s3 = 0.f;
    for (int t = 0; t < T_; t++) {
      float c = cs[bb * T_ + t];
      const float* wr = Wg + (size_t)(layer * T_ + t) * E_;
      s0 += c * wr[0]; s1 += c * wr[1]; s2 += c * wr[2]; s3 += c * wr[3];
    }
    float v[4] = {s0 / (float)N_, s1 / (float)N_, s2 / (float)N_, s3 / (float)N_};
    int i0 = 0;
    for (int e = 1; e < 4; e++) if (v[e] > v[i0]) i0 = e;
    int i1 = -1;
    for (int e = 0; e < 4; e++) {
      if (e == i0) continue;
      if (i1 < 0 || v[e] > v[i1]) i1 = e;
    }
    float ex = expf(v[i1] - v[i0]);
    float a = 1.f / (1.f + ex), q = ex / (1.f + ex);
    gg0 = (i0 == 0) ? a : ((i1 == 0) ? q : 0.f);
    gg1 = (i0 == 1) ? a : ((i1 == 1) ? q : 0.f);
    gg2 = (i0 == 2) ? a : ((i1 == 2) ? q : 0.f);
    gg3 = (i0 == 3) ? a : ((i1 == 3) ? q : 0.f);
  }
  #pragma unroll
  for (int m = 1; m < 32; m <<= 1) {
    gg0 += __shfl_xor(gg0, m); gg1 += __shfl_xor(gg1, m);
    gg2 += __shfl_xor(gg2, m); gg3 += __shfl_xor(gg3, m);
  }
  if (lane == 0) {
    float mm = (gg0 + gg1 + gg2 + gg3) * 0.25f;
    float d0 = gg0 - mm, d1 = gg1 - mm, d2 = gg2 - mm, d3 = gg3 - mm;
    float va = (d0 * d0 + d1 * d1 + d2 * d2 + d3 * d3) * 0.25f;
    loss_partial[layer] = 0.01f * (va / (mm * mm + 1e-10f));
  }
}

// ---------------- transpose + cast fp32 -> bf16 (K-contiguous operand prep) ----------
__global__ void transpose_cast_kernel(const float* __restrict__ src, bf16* __restrict__ dst,
                                      int R, int C, int Rp, int Cp,
                                      long long sStride, long long dStride) {
  __shared__ float tile[32][33];
  const float* s = src + (size_t)blockIdx.z * sStride;
  bf16* d = dst + (size_t)blockIdx.z * dStride;
  int r0 = blockIdx.x * 32, c0 = blockIdx.y * 32;
  int tx = threadIdx.x, ty = threadIdx.y;
  #pragma unroll
  for (int ii = 0; ii < 4; ii++) {
    int rl = ty * 4 + ii;
    int r = r0 + rl, c = c0 + tx;
    tile[rl][tx] = (r < R && c < C) ? s[(size_t)r * C + c] : 0.f;
  }
  __syncthreads();
  #pragma unroll
  for (int ii = 0; ii < 4; ii++) {
    int cl = ty * 4 + ii;
    int cd = c0 + cl, rd = r0 + tx;
    if (cd < Cp && rd < Rp)
      d[(size_t)cd * Rp + rd] = __float2bfloat16(tile[tx][cl]);
  }
}

// ---------------- We2 -> k-blocked W2B ---------------------------------------------
// grid (F/32, 4, L*E); dst[le][tb][kg][row96][8] = We2[le][f=kg*8+j][t=tb*96+row]
__global__ void repack_w2_kernel(const float* __restrict__ src, bf16* __restrict__ dst) {
  __shared__ float tile[32][96];
  int le = blockIdx.z, tb = blockIdx.y, f0 = blockIdx.x * 32;
  int tid = threadIdx.x;
  const float* s = src + (size_t)le * F_ * T_;
  for (int idx = tid; idx < 32 * 96; idx += 256) {
    int ff = idx / 96, tt = idx % 96;
    int t = tb * 96 + tt;
    tile[ff][tt] = (t < T_) ? s[(size_t)(f0 + ff) * T_ + t] : 0.f;
  }
  __syncthreads();
  bf16* d = dst + ((size_t)le * 4 + tb) * 196608 + (size_t)(f0 >> 3) * 768;
  for (int s2 = tid; s2 < 384; s2 += 256) {
    int kgl = s2 / 96, row = s2 % 96;
    bf16 v[8];
    #pragma unroll
    for (int j = 0; j < 8; j++) v[j] = __float2bfloat16(tile[kgl * 8 + j][row]);
    *(uint4*)(d + (size_t)kgl * 768 + row * 8) = *(const uint4*)v;
  }
}

// ---------------- RevIN + initial pack: x -> out (fp32), Abuf (bf16), colsum --------
__global__ __launch_bounds__(512) void revin_kernel(const float* __restrict__ x,
                                                    float* __restrict__ out,
                                                    bf16* __restrict__ Abuf,
                                                    float* __restrict__ cs0) {
  __shared__ float red[8][64][2];
  __shared__ float minv[64][2];
  __shared__ unsigned int Lt[64][177];   // 176 used cols (= TPAD/2 uints per row)

  const int b = blockIdx.x;
  const int n0 = blockIdx.y * 64;
  const int tid = threadIdx.x;
  const int nl = tid & 63, tq = tid >> 6;      // tq 0..7
  const int n = n0 + nl;
  const bool valid = (n < N_);
  const float* xp = x + ((size_t)b * T_ * N_ + n) * 3;
  const int tbeg = tq * 42, tend = tbeg + 42;  // 8*42 = 336 = T_

  // pass 1: partial sums over this thread's t-range
  float s1 = 0.f, s2 = 0.f;
  if (valid) {
    for (int t = tbeg; t < tend; t++) {
      float v = xp[(size_t)t * N_ * 3];
      s1 += v; s2 += v * v;
    }
  }
  red[tq][nl][0] = s1; red[tq][nl][1] = s2;
  __syncthreads();
  if (tid < 64) {
    float a = 0.f, c = 0.f;
    #pragma unroll
    for (int q = 0; q < 8; q++) { a += red[q][tid][0]; c += red[q][tid][1]; }
    float mu = a / (float)T_;
    float var = c / (float)T_ - mu * mu;
    minv[tid][0] = mu;
    minv[tid][1] = 1.f / sqrtf(var + 1e-5f);
  }
  // zero the pad cols (t in [336,352) -> uint cols 168..175): 64 rows x 8 cols
  {
    int r = tid >> 3, c = 168 + (tid & 7);
    Lt[r][c] = 0u;
  }
  __syncthreads();

  const float mu = minv[nl][0], inv = minv[nl][1];
  // pass 2: normalize, write out (coalesced), stage packed bf16 pairs into LDS,
  // and accumulate colsum over this block's 64 n's (wave butterfly, lane0 atomic).
  for (int t = tbeg; t < tend; t += 2) {
    float v0 = 0.f, v1 = 0.f;
    if (valid) {
      v0 = (xp[(size_t)t * N_ * 3] - mu) * inv;
      v1 = (xp[(size_t)(t + 1) * N_ * 3] - mu) * inv;
      out[((size_t)b * T_ + t) * N_ + n] = v0;
      out[((size_t)b * T_ + t + 1) * N_ + n] = v1;
    }
    float c0 = v0, c1 = v1;
    #pragma unroll
    for (int m = 1; m < 64; m <<= 1) {
      c0 += __shfl_xor(c0, m);
      c1 += __shfl_xor(c1, m);
    }
    if (nl == 0) {
      atomicAdd(cs0 + b * T_ + t, c0);
      atomicAdd(cs0 + b * T_ + t + 1, c1);
    }
    bf16 h0 = __float2bfloat16(v0), h1 = __float2bfloat16(v1);
    unsigned int u = (unsigned int)*(unsigned short*)&h0 |
                     ((unsigned int)*(unsigned short*)&h1 << 16);
    Lt[nl][t >> 1] = u;
  }
  __syncthreads();

  // copy-out: 64 rows x 176 uints = 11264 uints, 22 per thread, coalesced
  unsigned int* abase = (unsigned int*)(Abuf + ((size_t)b * NPAD + n0) * TPAD);
  #pragma unroll
  for (int k = 0; k < 22; k++) {
    int idx = tid + k * 512;
    int row = idx / 176, c = idx % 176;
    abase[(size_t)row * (TPAD / 2) + c] = Lt[row][c];
  }
}

// ---------------- GEMM1: h[pair] = gate * relu(Abuf[b] @ We1[l,e] + be1) ------------
// h written in blocked layout (see top). 2-phase pipelined. Gating inline (wave0);
// balance loss by wave1 of block (0,0,0). LDS bank-swizzled (see file-top comment):
// within each 64B row-chunk, k-part K is stored at slot K ^ ((row>>1)&3); fragment
// reads use kx = (quad ^ ((l15>>1)&3))*8 -> 8 distinct bank-starts per issue group.
__global__ __launch_bounds__(256) void gemm1_kernel(
    const bf16* __restrict__ Abuf, const bf16* __restrict__ W1T,
    const float* __restrict__ be1, const float* __restrict__ cs,
    const float* __restrict__ Wg, float* __restrict__ loss_partial,
    bf16* __restrict__ h, int layer) {
  // buf b: A = S1 + b*8192 (128x32), B = S1 + b*8192 + 4096 (128x32)
  __shared__ __align__(16) bf16 S1[16384];
  __shared__ float bias_s[128];
  __shared__ float lgs[4];

  const int tid = threadIdx.x;
  const int w = tid >> 6, lane = tid & 63;
  const int pair = blockIdx.z;
  const int b = pair >> 1;
  const int m0 = blockIdx.y * 128;  // n-dim
  const int f0 = blockIdx.x * 128;

  gate_logits(cs, Wg, layer, b, lgs, tid);
  if (blockIdx.x == 0 && blockIdx.y == 0 && pair == 0 && w == 1)
    balance_loss(cs, Wg, layer, lane, loss_partial);
  __syncthreads();
  int i0, i1; float ga, gb;
  top2_from(lgs, i0, i1, ga, gb);
  const int e = __builtin_amdgcn_readfirstlane((pair & 1) ? i1 : i0);
  const float gate = (pair & 1) ? gb : ga;

  const bf16* Ag = Abuf + (size_t)b * NPAD * TPAD + (size_t)m0 * TPAD;
  const bf16* Bg = W1T + ((size_t)(layer * E_ + e) * F_ + f0) * TPAD;
  if (tid < 128) bias_s[tid] = be1[(size_t)(layer * E_ + e) * F_ + f0 + tid];

  f32x4 acc[4][4];
  const f32x4 zero = {0.f, 0.f, 0.f, 0.f};
  #pragma unroll
  for (int i = 0; i < 4; i++)
    #pragma unroll
    for (int j = 0; j < 4; j++) acc[i][j] = zero;

  const int wm = w >> 1, wn = w & 1;
  const int lrow = lane >> 2;          // 64B-coalesced staging (4 lanes per row)
  // content swizzle: k-part for this lane = (lane&3) ^ ((row>>1)&3)
  const int lkoff = (((lane & 3) ^ ((lrow >> 1) & 3))) * 8;
  const int quad = lane >> 4;
  const int l15 = lane & 15;
  // fragment-read k-slot offset (inverse of the staging swizzle), loop-invariant
  const int kx = (quad ^ ((l15 >> 1) & 3)) << 3;

  auto stage1 = [&](int k, int buf) {
    const int k0 = k * 32;
    bf16* As = S1 + buf * 8192;
    bf16* Bs = As + 4096;
    #pragma unroll
    for (int i = 0; i < 2; i++) {
      int r = (w * 2 + i) * 16 + lrow;
      async_copy16(Ag + (size_t)r * TPAD + k0 + lkoff, As + (w * 2 + i) * 512);
      async_copy16(Bg + (size_t)r * TPAD + k0 + lkoff, Bs + (w * 2 + i) * 512);
    }
  };

  stage1(0, 0);
  pipe_barrier_full();

  for (int kk = 0; kk < TPAD / 32; ++kk) {
    if (kk < TPAD / 32 - 1) stage1(kk + 1, (kk + 1) & 1);
    const bf16* As = S1 + (kk & 1) * 8192;
    const bf16* Bs = As + 4096;
    bf16x8 af[4], bfr[4];
    #pragma unroll
    for (int mi = 0; mi < 4; mi++)
      af[mi] = *(const bf16x8*)(As + (wm * 4 + mi) * 512 + l15 * 32 + kx);
    #pragma unroll
    for (int ni = 0; ni < 4; ni++)
      bfr[ni] = *(const bf16x8*)(Bs + (wn * 4 + ni) * 512 + l15 * 32 + kx);
    #pragma unroll
    for (int mi = 0; mi < 4; mi++)
      #pragma unroll
      for (int ni = 0; ni < 4; ni++)
        acc[mi][ni] = __builtin_amdgcn_mfma_f32_16x16x32_bf16(af[mi], bfr[ni], acc[mi][ni], 0, 0, 0);
    pipe_barrier_vm0();
  }

  // epilogue: bias + relu + gate, LDS transpose (bank-swizzled: colgroup ^ 2*quad),
  // then blocked-layout h stores.
  bf16* tw0 = S1 + w * 1024;          // per-wave private scratch (buf0 A region)
  bf16* tw1 = S1 + 4096 + w * 1024;   // per-wave private scratch (buf0 B region)
  // this wave's rows live in nb = m0/64 + wm, rows mi*16 + (lane>>2)
  size_t hb = (size_t)pair * 786432 + (size_t)((m0 >> 6) + wm) * 131072;
  const int kgbase = (f0 >> 3) + wn * 8 + (lane & 3) * 2;
  #pragma unroll
  for (int mi = 0; mi < 4; mi++) {
    bf16* tw = (mi & 1) ? tw1 : tw0;
    #pragma unroll
    for (int ni = 0; ni < 4; ni++) {
      float bias = bias_s[wn * 64 + ni * 16 + l15];
      #pragma unroll
      for (int r = 0; r < 4; r++) {
        float v = acc[mi][ni][r] + bias;
        v = fmaxf(v, 0.f) * gate;
        int colhi = (2 * ni + (l15 >> 3)) ^ (quad << 1);   // swizzled 8-el colgroup
        tw[(quad * 4 + r) * 64 + colhi * 8 + (l15 & 7)] = __float2bfloat16(v);
      }
    }
    int row = lane >> 2;            // 0..15
    int k2 = (row >> 2) & 3;        // quad-of-row (write-side swizzle key)
    const uint4* sp = (const uint4*)(tw + row * 64 + (((lane & 3) ^ k2) << 4));
    uint4 d0 = sp[0];
    uint4 d1 = sp[1];
    bf16* dp = h + hb + (size_t)kgbase * 512 + (mi * 16 + row) * 8;
    *(uint4*)dp = d0;
    *(uint4*)(dp + 512) = d1;
  }
}

// ---------------- GEMM2+pack fused: both experts per block, K=4096 ------------------
// out[b,t,n] += h@We2 (both experts) + gated be2; Abuf[b,n,t] = bf16(out).
// Gating inline (wave0). Epilogue also accumulates colsum for the NEXT layer's
// gating (LDS reduce + one global atomic per t; layer 0 only).
// Pipeline: A 3-buffered 2-ahead, B 2-buffered 1-ahead, counted vmcnt(2).
// XCD swizzle keeps the 4 t-tiles of a (b,n)-group on one XCD.
#define CT_STRIDE 104
__global__ __launch_bounds__(256) void gemm2_kernel(
    const bf16* __restrict__ h, const bf16* __restrict__ W2B,
    const float* __restrict__ be2, const float* __restrict__ cs_cur,
    float* __restrict__ cs_next, const float* __restrict__ Wg,
    float* __restrict__ out, bf16* __restrict__ Abuf, int layer) {
  // S layout (els): A0@0 A1@4096 A2@8192 | B0@12288 B1@18432 | end 24576 (48KB).
  // epilogue reuses first 64*CT_STRIDE = 6656 els as bf16 C-tile.
  __shared__ __align__(16) bf16 S[24576];
  __shared__ float bias_t[96];
  __shared__ float lgs[4];
  __shared__ float csl[96];

  const int tid = threadIdx.x;
  const int w = tid >> 6, lane = tid & 63;
  const int id = blockIdx.x;           // 0..767
  const int u = id & 7;                // XCD (round-robin heuristic)
  const int v = id >> 3;               // 0..95
  const int tt = v & 3;
  const int pn = u + 8 * (v >> 2);     // 0..191
  const int b = pn / 6, nt = pn % 6;
  const int n0 = nt * 64, t0 = tt * 96;

  gate_logits(cs_cur, Wg, layer, b, lgs, tid);
  if (tid < 96) csl[tid] = 0.f;
  __syncthreads();
  int i0, i1; float g0, g1;
  top2_from(lgs, i0, i1, g0, g1);
  const int e0 = __builtin_amdgcn_readfirstlane(i0);
  const int e1 = __builtin_amdgcn_readfirstlane(i1);

  const bf16* Agb0 = h + ((size_t)(b * 2) * 6 + nt) * 131072;
  const bf16* Agb1 = h + ((size_t)(b * 2 + 1) * 6 + nt) * 131072;
  const bf16* Bgb0 = W2B + ((size_t)(layer * E_ + e0) * 4 + tt) * 196608;
  const bf16* Bgb1 = W2B + ((size_t)(layer * E_ + e1) * 4 + tt) * 196608;
  const int quad = lane >> 4, l15 = lane & 15;
  const int wm = w >> 1, wt = w & 1;   // wave tile: 32(n) x 48(t)

  if (tid < 96) {
    int t = t0 + tid;
    bias_t[tid] = (t < T_)
        ? g0 * be2[(layer * E_ + e0) * T_ + t] + g1 * be2[(layer * E_ + e1) * T_ + t]
        : 0.f;
  }
  // drain all prior VMEM (gating + divergent bias loads) so per-thread vmcnt is
  // exactly the 5 staging loads per K-step from here on.
  pipe_barrier_full();

  f32x4 acc[2][3];
  const f32x4 zero = {0.f, 0.f, 0.f, 0.f};
  #pragma unroll
  for (int i = 0; i < 2; i++)
    #pragma unroll
    for (int jj = 0; jj < 3; jj++) acc[i][jj] = zero;

  const int aoff = w * 1024 + lane * 8;   // per-thread staging offsets (els)
  const int boff = w * 1536 + lane * 8;

  auto stageA = [&](const bf16* Aj, int buf) {   // 2 loads/thread
    bf16* As2 = S + buf * 4096;
    async_copy16(Aj + aoff, As2 + w * 1024);
    async_copy16(Aj + aoff + 512, As2 + w * 1024 + 512);
  };
  auto stageB = [&](const bf16* Bj, int buf) {   // 3 loads/thread
    bf16* Bs2 = S + 12288 + buf * 6144;
    async_copy16(Bj + boff, Bs2 + w * 1536);
    async_copy16(Bj + boff + 512, Bs2 + w * 1536 + 512);
    async_copy16(Bj + boff + 1024, Bs2 + w * 1536 + 1024);
  };

  auto compute = [&](int bufA, int bufB) {
    const bf16* As2 = S + bufA * 4096;
    const bf16* Bs2 = S + 12288 + bufB * 6144;
    #pragma unroll
    for (int w32 = 0; w32 < 2; w32++) {
      const int kg = w32 * 4 + quad;
      bf16x8 af[2], bfr[3];
      #pragma unroll
      for (int mi = 0; mi < 2; mi++)
        af[mi] = *(const bf16x8*)(As2 + kg * 512 + (wm * 32 + mi * 16 + l15) * 8);
      #pragma unroll
      for (int ni = 0; ni < 3; ni++)
        bfr[ni] = *(const bf16x8*)(Bs2 + kg * 768 + (wt * 48 + ni * 16 + l15) * 8);
      #pragma unroll
      for (int mi = 0; mi < 2; mi++)
        #pragma unroll
        for (int ni = 0; ni < 3; ni++)
          acc[mi][ni] = __builtin_amdgcn_mfma_f32_16x16x32_bf16(af[mi], bfr[ni], acc[mi][ni], 0, 0, 0);
    }
  };

  // prologue: B(0)->b0, A(0)->a0, A(1)->a1; wait all but the newest 2 (A(1)).
  stageB(Bgb0, 0);
  stageA(Agb0, 0);
  stageA(Agb0 + 4096, 1);
  G2_WAITN(2);

  const bf16* aNext = Agb0 + 2 * 4096;  // A(2)
  const bf16* bNext = Bgb0 + 6144;      // B(1)

  // main loop: k = 0..59, 6 steps per iteration (lcm of 3 A-bufs, 2 B-bufs).
  // Step k: issue B(k+1), issue A(k+2) (newest), compute(k), wait vmcnt(2).
  #pragma unroll 1
  for (int j = 0; j < 10; ++j) {
    const int k = j * 6;
#define G2S(i, bB1, bA2, cA, cB)                              \
    stageB(bNext, bB1);                                       \
    stageA(aNext, bA2);                                       \
    bNext = (k + (i) == 30) ? Bgb1 : bNext + 6144;            \
    aNext = (k + (i) == 29) ? Agb1 : aNext + 4096;            \
    compute(cA, cB);                                          \
    G2_WAITN(2);
    G2S(0, 1, 2, 0, 0)
    G2S(1, 0, 0, 1, 1)
    G2S(2, 1, 1, 2, 0)
    G2S(3, 0, 2, 0, 1)
    G2S(4, 1, 0, 1, 0)
    G2S(5, 0, 1, 2, 1)
#undef G2S
  }

  // tail: k = 60..63
  stageB(bNext, 1);          // B(61)
  stageA(aNext, 2);          // A(62)
  bNext += 6144; aNext += 4096;
  compute(0, 0);             // k=60
  G2_WAITN(2);

  stageB(bNext, 0);          // B(62)
  stageA(aNext, 0);          // A(63)
  bNext += 6144;
  compute(1, 1);             // k=61
  G2_WAITN(2);

  stageB(bNext, 1);          // B(63)
  compute(2, 0);             // k=62
  G2_WAITN(0);

  compute(0, 1);             // k=63
  pipe_barrier_full();       // all ds_reads done before S reuse below

  // ---- fused pack epilogue: residual merge -> out (fp32) + C-tile -> LDS (bf16)
  //      + per-t colsum partials for next layer's gating
  float ps[3] = {0.f, 0.f, 0.f};
  #pragma unroll
  for (int mi = 0; mi < 2; mi++) {
    #pragma unroll
    for (int ni = 0; ni < 3; ni++) {
      int nloc_b = wm * 32 + mi * 16 + quad * 4;
      int tloc = wt * 48 + ni * 16 + l15;
      int t = t0 + tloc;
      #pragma unroll
      for (int r = 0; r < 4; r++) {
        int nloc = nloc_b + r;
        int n = n0 + nloc;
        float vv = 0.f;
        if (n < N_ && t < T_) {
          size_t q = ((size_t)b * T_ + t) * N_ + n;
          vv = out[q] + acc[mi][ni][r] + bias_t[tloc];
          out[q] = vv;
        }
        ps[ni] += vv;   // vv==0 outside valid region
        S[nloc * CT_STRIDE + tloc] = __float2bfloat16(vv);
      }
    }
  }
  if (layer == 0) {
    #pragma unroll
    for (int ni = 0; ni < 3; ni++)
      atomicAdd(&csl[wt * 48 + ni * 16 + l15], ps[ni]);
  }
  __syncthreads();
  // transpose-store Abuf rows (coalesced 16B segments); pad cols (t>=T) get zeros
  #pragma unroll
  for (int it = 0; it < 3; ++it) {
    int idx = tid + it * 256;          // < 768 = 64 rows * 12 segs
    int row = idx / 12, seg = idx % 12;
    int t = t0 + seg * 8;
    if (t < TPAD)
      *(uint4*)(Abuf + ((size_t)b * NPAD + n0 + row) * TPAD + t) =
          *(const uint4*)(S + row * CT_STRIDE + seg * 8);
  }
  if (layer == 0 && tid < 96) {
    int t = t0 + tid;
    if (t < T_) atomicAdd(cs_next + b * T_ + t, csl[tid]);
  }
}

// ---------------- projection head: fused two-stage MFMA -----------------------------
// 64 rows/block, grid (6,B) = 192 blocks; one 16-row MFMA strip per wave.
#define HS_STRIDE 104  // 96 + 8 pad (208B row stride, 16B-aligned)
__global__ __launch_bounds__(256) void proj_kernel(
    const bf16* __restrict__ Abuf, const bf16* __restrict__ P1T, const float* __restrict__ P1b,
    const bf16* __restrict__ P2T, const float* __restrict__ P2b,
    const float* __restrict__ loss_partial, float* __restrict__ dout) {
  __shared__ __align__(16) bf16 Hs[64 * HS_STRIDE];
  const int tid = threadIdx.x;
  const int w = tid >> 6, lane = tid & 63;
  const int quad = lane >> 4, l15 = lane & 15;
  const int b = blockIdx.y;
  const int m0 = blockIdx.x * 64;
  const int row = w * 16;              // wave's row strip within the 64-row tile

  f32x4 acc1[6];
  const f32x4 zero = {0.f, 0.f, 0.f, 0.f};
  #pragma unroll
  for (int j = 0; j < 6; j++) acc1[j] = zero;

  const bf16* Arow = Abuf + ((size_t)b * NPAD + m0 + row) * TPAD;
  for (int kk = 0; kk < TPAD / 32; ++kk) {
    bf16x8 af, bfr[6];
    af = *(const bf16x8*)(Arow + (size_t)l15 * TPAD + kk * 32 + quad * 8);
    #pragma unroll
    for (int ni = 0; ni < 6; ni++)
      bfr[ni] = *(const bf16x8*)(P1T + (size_t)(ni * 16 + l15) * TPAD + kk * 32 + quad * 8);
    #pragma unroll
    for (int ni = 0; ni < 6; ni++)
      acc1[ni] = __builtin_amdgcn_mfma_f32_16x16x32_bf16(af, bfr[ni], acc1[ni], 0, 0, 0);
  }

  #pragma unroll
  for (int ni = 0; ni < 6; ni++) {
    float bias = P1b[ni * 16 + l15];
    #pragma unroll
    for (int r = 0; r < 4; r++) {
      float x = acc1[ni][r] + bias;
      float t = 1.f - 2.f / (__expf(2.f * x) + 1.f);
      Hs[(row + quad * 4 + r) * HS_STRIDE + ni * 16 + l15] = __float2bfloat16(t);
    }
  }
  __syncthreads();

  #pragma unroll
  for (int half = 0; half < 2; ++half) {
    f32x4 acc2[6];
    #pragma unroll
    for (int j = 0; j < 6; j++) acc2[j] = zero;

    #pragma unroll
    for (int kk = 0; kk < 3; ++kk) {
      bf16x8 af, bfr[6];
      af = *(const bf16x8*)(Hs + (row + l15) * HS_STRIDE + kk * 32 + quad * 8);
      #pragma unroll
      for (int ni = 0; ni < 6; ni++)
        bfr[ni] = *(const bf16x8*)(P2T + (size_t)((half * 6 + ni) * 16 + l15) * P_ + kk * 32 + quad * 8);
      #pragma unroll
      for (int ni = 0; ni < 6; ni++)
        acc2[ni] = __builtin_amdgcn_mfma_f32_16x16x32_bf16(af, bfr[ni], acc2[ni], 0, 0, 0);
    }

    #pragma unroll
    for (int ni = 0; ni < 6; ni++) {
      int jj = (half * 6 + ni) * 16 + l15;
      float bias = P2b[jj];
      int pout = jj >> 1;
      #pragma unroll
      for (int r = 0; r < 4; r++) {
        int n = m0 + row + quad * 4 + r;
        if (n < N_) {
          float s = acc2[ni][r] + bias;
          size_t o = ((size_t)b * P_ + pout) * N_ + n;
          if ((jj & 1) == 0) {
            dout[o] = s;
          } else {
            float sp = (s > 20.f) ? s : log1pf(__expf(s));
            dout[(size_t)B_ * P_ * N_ + 1 + o] = sp + 1e-6f;
          }
        }
      }
    }
  }
  if (b == 0 && blockIdx.x == 0 && tid == 0)
    dout[(size_t)B_ * P_ * N_] = loss_partial[0] + loss_partial[1];
}

// ----------------------------------------------------------------------------------
extern "C" void kernel_launch(void* const* d_in, const int* in_sizes, int n_in,
                              void* d_out, int out_size, void* d_ws, size_t ws_size,
                              hipStream_t stream) {
  const float* x   = (const float*)d_in[0];
  const float* Wg  = (const float*)d_in[11];
  const float* We1 = (const float*)d_in[12];
  const float* be1 = (const float*)d_in[13];
  const float* We2 = (const float*)d_in[14];
  const float* be2 = (const float*)d_in[15];
  const float* P1w = (const float*)d_in[16];
  const float* P1b = (const float*)d_in[17];
  const float* P2w = (const float*)d_in[18];
  const float* P2b = (const float*)d_in[19];

  char* ws = (char*)d_ws;
  size_t off = 0;
  auto alloc = [&](size_t bytes) -> void* {
    void* p = ws + off;
    off += (bytes + 255) & ~(size_t)255;
    return p;
  };
  float* out        = (float*)alloc((size_t)B_ * T_ * N_ * 4);
  bf16*  Abuf       = (bf16*) alloc((size_t)B_ * NPAD * TPAD * 2);
  bf16*  W1T        = (bf16*) alloc((size_t)L_ * E_ * F_ * TPAD * 2);
  bf16*  W2B        = (bf16*) alloc((size_t)L_ * E_ * 4 * 196608 * 2);
  bf16*  P1T        = (bf16*) alloc((size_t)P_ * TPAD * 2);
  bf16*  P2T        = (bf16*) alloc((size_t)2 * P_ * P_ * 2);
  bf16*  h          = (bf16*) alloc((size_t)B_ * 2 * 786432 * 2);
  float* colsum     = (float*)alloc((size_t)2 * B_ * T_ * 4);   // [layer][B][T]
  float* loss_part  = (float*)alloc(2 * 4);
  if (ws_size < off) return;  // workspace too small — bail instead of corrupting

  dim3 tb(32, 8);
  transpose_cast_kernel<<<dim3(11, 64, 8), tb, 0, stream>>>(
      We1, W1T, T_, F_, TPAD, F_, (long long)T_ * F_, (long long)F_ * TPAD);
  repack_w2_kernel<<<dim3(64, 4, 8), 256, 0, stream>>>(We2, W2B);
  transpose_cast_kernel<<<dim3(11, 3, 1), tb, 0, stream>>>(
      P1w, P1T, T_, P_, TPAD, P_, 0, 0);
  transpose_cast_kernel<<<dim3(3, 6, 1), tb, 0, stream>>>(
      P2w, P2T, P_, 2 * P_, P_, 2 * P_, 0, 0);

  hipMemsetAsync(colsum, 0, (size_t)2 * B_ * T_ * 4, stream);
  revin_kernel<<<dim3(B_, 6), 512, 0, stream>>>(x, out, Abuf, colsum);

  for (int l = 0; l < L_; ++l) {
    const float* cs = colsum + (size_t)l * B_ * T_;
    gemm1_kernel<<<dim3(16, 3, 64), 256, 0, stream>>>(
        Abuf, W1T, be1, cs, Wg, loss_part, h, l);
    gemm2_kernel<<<768, 256, 0, stream>>>(
        h, W2B, be2, cs, colsum + (size_t)B_ * T_, Wg, out, Abuf, l);
  }

  proj_kernel<<<dim3(6, B_), 256, 0, stream>>>(Abuf, P1T, P1b, P2T, P2b, loss_part,
                                               (float*)d_out);
}